// Round 6
// baseline (486.939 us; speedup 1.0000x reference)
//
#include <hip/hip_runtime.h>
#include <cstdint>
#include <math.h>

// ---------------------------------------------------------------------------
// ParallelAttention (GPT-NeoX style), MI355X gfx950.
//   SEQ=2048 BATCH=2 HID=2048 NH=16 HD=128, causal mask, RoPE full head dim.
// INTERFACE (established R0-R7): fp32 inputs, fp32 output, inputs resolved by
//   element count (w_dense = LAST 4194304 match; mask unused).
// R9: GEMMs on m97 structure (bf16 pre-convert + global_load_lds w16).
// R10 FAILED: 512-thr attn + reg ping-pong prefetch -> VGPR spills.
// R11: attn 4-wave + gload_lds K/V (pre-swizzled src + XOR read). 133us.
// R12 FAILED: wvw aliased Vt. R13 fixed (wvw in d_out) but dbuf REGRESSED
//   attn 133->154 (m99/m132 lesson: explicit LDS dbuf loses; 80K LDS +
//   compiler vmcnt conservatism around runtime-indexed buffer reads).
// R14: single-buffer R11 staging structure + SPLIT-K:
//   - qt>=9 blocks split into two halves of (qt+1) k-tiles each with own
//     (m,l,o); f32 partials in d_out scratch (29.8MB; wvw dead by attn;
//     partials dead before dense_gemm). combine kernel merges -> ctx.
//   - critical chain 32 -> 18 tiles; 736 blocks, longest-first static order.
//   - riders kept (R13-proven): defer-max, diag-skip, log2 softmax, P
//     stride-64 XOR swizzle, setprio. LDS 48K -> up to 3 blocks/CU.
// MFMA 16x16x32 bf16: A/B row=lane&15, k=(lane>>4)*8+j; C/D col=lane&15,
//   row=(lane>>4)*4+reg (verified m89/m91).
// global_load_lds: LDS dest is wave-uniform base + lane*16B (m104/m108) --
//   LDS must be LINEAR, source address is per-lane (pre-swizzle there).
// ---------------------------------------------------------------------------

typedef unsigned short u16;
typedef __bf16 bf16x8 __attribute__((ext_vector_type(8)));
typedef float floatx4 __attribute__((ext_vector_type(4)));

#define SEQ 2048
#define BATCH 2
#define HID 2048
#define NH 16
#define HD 128

__device__ __forceinline__ u16 f2bf(float f) {
  union { float f; uint32_t u; } v; v.f = f;
  uint32_t u = v.u;
  return (u16)((u + 0x7FFFu + ((u >> 16) & 1u)) >> 16);
}

// pack 8 fp32 -> 8 bf16 (RNE) and store 16B
__device__ __forceinline__ void st8_bf16(u16* dst, const float* s) {
  uint32_t pk[4];
#pragma unroll
  for (int j = 0; j < 4; j++)
    pk[j] = (uint32_t)f2bf(s[2 * j]) | ((uint32_t)f2bf(s[2 * j + 1]) << 16);
  *(uint4*)dst = make_uint4(pk[0], pk[1], pk[2], pk[3]);
}

// async global->LDS, 16B per lane; lds base must be wave-uniform
__device__ __forceinline__ void gl16(const u16* g, u16* l) {
  __builtin_amdgcn_global_load_lds(
      (const __attribute__((address_space(1))) void*)g,
      (__attribute__((address_space(3))) void*)l, 16, 0, 0);
}

// ------- input conversion: w_qkv K/Q tiles, hidden, V tiles -> bf16 ---------
// wb tile order: [K head 0..15][Q head 0..15]; src K h = 3h+1, Q h = 3h.
// V tiles (blk >= 8192) -> wvw (lives in d_out scratch), src h = 3h+2.
__global__ __launch_bounds__(256) void cvt_inputs(
    const float* __restrict__ W, const float* __restrict__ Hid,
    u16* __restrict__ wb, u16* __restrict__ Ah, u16* __restrict__ wvw) {
  const int blk = blockIdx.x;
  const int c0 = threadIdx.x * 8;
  const float* src;
  u16* dst;
  if (blk < 4096) {
    int dt = blk >> 7, r = blk & 127;
    int srow = (dt < 16) ? ((dt * 3 + 1) * 128 + r) : (((dt - 16) * 3) * 128 + r);
    src = W + (size_t)srow * HID;
    dst = wb + (size_t)blk * HID;
  } else if (blk < 8192) {
    int r = blk - 4096;
    src = Hid + (size_t)r * HID;
    dst = Ah + (size_t)r * HID;
  } else {
    int v = blk - 8192;  // 0..2047
    int h = v >> 7, r = v & 127;
    src = W + (size_t)((h * 3 + 2) * 128 + r) * HID;
    dst = wvw + (size_t)v * HID;
  }
  float t[8];
  *(floatx4*)&t[0] = *(const floatx4*)(src + c0);
  *(floatx4*)&t[4] = *(const floatx4*)(src + c0 + 4);
  st8_bf16(dst + c0, t);
}

// ---------------- w_dense fp32 -> bf16 --------------------------------------
__global__ __launch_bounds__(256) void cvt_wd(const float* __restrict__ W,
                                              u16* __restrict__ wd) {
  const int r = blockIdx.x;
  const int c0 = threadIdx.x * 8;
  float t[8];
  const float* src = W + (size_t)r * HID;
  *(floatx4*)&t[0] = *(const floatx4*)(src + c0);
  *(floatx4*)&t[4] = *(const floatx4*)(src + c0 + 4);
  st8_bf16(wd + (size_t)r * HID + c0, t);
}

// ---------------- QK projection: bf16 @ bf16, gload_lds both operands -------
__global__ __launch_bounds__(256, 2) void qkv_qk(
    const u16* __restrict__ Ah, const u16* __restrict__ wb,
    const float* __restrict__ bias, u16* __restrict__ Qw,
    u16* __restrict__ Kw) {
  __shared__ __align__(16) u16 As[128 * 64];
  __shared__ __align__(16) u16 Bs[128 * 64];
  const int tid = threadIdx.x;
  const int wv = tid >> 6, lane = tid & 63;
  const int quad = lane >> 4, l16 = lane & 15;
  const int wt = blockIdx.x;  // 0..15 = K head wt, 16..31 = Q head wt-16
  const int bm = blockIdx.y;
  const int rowA0 = bm * 128;
  const int wm = (wv >> 1) * 64;
  const int wn = (wv & 1) * 32;
  const int ntoff[4] = {wn, wn + 16, wn + 64, wn + 80};

  const int lrow = wv * 32 + (lane >> 3);
  const int lcol = (lane & 7) * 8;
  const u16* Ag = Ah + (size_t)(rowA0 + lrow) * HID + lcol;
  const u16* Bg = wb + ((size_t)wt * 128 + lrow) * HID + lcol;
  u16* Al = &As[(wv * 32) * 64];  // wave-uniform
  u16* Bl = &Bs[(wv * 32) * 64];

  floatx4 acc[4][4];
#pragma unroll
  for (int i = 0; i < 4; i++)
#pragma unroll
    for (int j = 0; j < 4; j++) acc[i][j] = (floatx4){0.f, 0.f, 0.f, 0.f};

  for (int kb = 0; kb < HID; kb += 64) {
#pragma unroll
    for (int j = 0; j < 4; j++) {
      gl16(Ag + (size_t)j * 8 * HID + kb, Al + j * 8 * 64);
      gl16(Bg + (size_t)j * 8 * HID + kb, Bl + j * 8 * 64);
    }
    __syncthreads();  // drains vmcnt(0): LDS tiles ready
#pragma unroll
    for (int ks = 0; ks < 64; ks += 32) {
      bf16x8 af[4], bfr[4];
#pragma unroll
      for (int mi = 0; mi < 4; mi++)
        af[mi] = *(const bf16x8*)&As[(wm + mi * 16 + l16) * 64 + ks + quad * 8];
#pragma unroll
      for (int ni = 0; ni < 4; ni++)
        bfr[ni] = *(const bf16x8*)&Bs[(ntoff[ni] + l16) * 64 + ks + quad * 8];
#pragma unroll
      for (int mi = 0; mi < 4; mi++)
#pragma unroll
        for (int ni = 0; ni < 4; ni++)
          acc[mi][ni] = __builtin_amdgcn_mfma_f32_16x16x32_bf16(
              af[mi], bfr[ni], acc[mi][ni], 0, 0, 0);
    }
    __syncthreads();  // all waves done reading before next gload_lds overwrite
  }

  // epilogue: bias + RoPE (inline cos/sin)
  const int seg = (wt < 16) ? 1 : 0;  // 1=K, 0=Q
  const int head = wt & 15;
  u16* dst = seg ? Kw : Qw;
  float bv[4];
#pragma unroll
  for (int ni = 0; ni < 4; ni++)
    bv[ni] = bias[(head * 3 + seg) * 128 + ntoff[ni] + l16];
  const float RC = 0.20762050593045951f;  // log2(10000)/64
  const float f0 = exp2f(-(float)(wn + l16) * RC);
  const float f1 = exp2f(-(float)(wn + 16 + l16) * RC);

#pragma unroll
  for (int mi = 0; mi < 4; mi++) {
#pragma unroll
    for (int reg = 0; reg < 4; reg++) {
      int r = rowA0 + wm + mi * 16 + quad * 4 + reg;
      int s = r >> 1, b = r & 1;
      size_t base = ((size_t)(b * NH + head) * SEQ + s) * HD;
      float sv, cv;
      sincosf((float)s * f0, &sv, &cv);
      {
        float lo = acc[mi][0][reg] + bv[0];
        float hi = acc[mi][2][reg] + bv[2];
        dst[base + wn + l16] = f2bf(lo * cv - hi * sv);
        dst[base + wn + l16 + 64] = f2bf(hi * cv + lo * sv);
      }
      sincosf((float)s * f1, &sv, &cv);
      {
        float lo = acc[mi][1][reg] + bv[1];
        float hi = acc[mi][3][reg] + bv[3];
        dst[base + wn + 16 + l16] = f2bf(lo * cv - hi * sv);
        dst[base + wn + 16 + l16 + 64] = f2bf(hi * cv + lo * sv);
      }
    }
  }
}

// ---------------- V projection: pure gload_lds (wvw in d_out scratch) -------
__global__ __launch_bounds__(256, 2) void qkv_v(
    const u16* __restrict__ Ah, const u16* __restrict__ wvw,
    const float* __restrict__ bias, u16* __restrict__ Vt) {
  __shared__ __align__(16) u16 As[128 * 64];
  __shared__ __align__(16) u16 Bs[128 * 64];
  const int tid = threadIdx.x;
  const int wv = tid >> 6, lane = tid & 63;
  const int quad = lane >> 4, l16 = lane & 15;
  const int head = blockIdx.x;  // 0..15
  const int bm = blockIdx.y;
  const int rowA0 = bm * 128;
  const int wm = (wv >> 1) * 64;
  const int wn = (wv & 1) * 32;
  const int ntoff[4] = {wn, wn + 16, wn + 64, wn + 80};

  const int lrow = wv * 32 + (lane >> 3);
  const int lcol = (lane & 7) * 8;
  const u16* Ag = Ah + (size_t)(rowA0 + lrow) * HID + lcol;
  const u16* Bg = wvw + ((size_t)head * 128 + lrow) * HID + lcol;
  u16* Al = &As[(wv * 32) * 64];
  u16* Bl = &Bs[(wv * 32) * 64];

  floatx4 acc[4][4];
#pragma unroll
  for (int i = 0; i < 4; i++)
#pragma unroll
    for (int j = 0; j < 4; j++) acc[i][j] = (floatx4){0.f, 0.f, 0.f, 0.f};

  for (int kb = 0; kb < HID; kb += 64) {
#pragma unroll
    for (int j = 0; j < 4; j++) {
      gl16(Ag + (size_t)j * 8 * HID + kb, Al + j * 8 * 64);
      gl16(Bg + (size_t)j * 8 * HID + kb, Bl + j * 8 * 64);
    }
    __syncthreads();
#pragma unroll
    for (int ks = 0; ks < 64; ks += 32) {
      bf16x8 af[4], bfr[4];
#pragma unroll
      for (int mi = 0; mi < 4; mi++)
        af[mi] = *(const bf16x8*)&As[(wm + mi * 16 + l16) * 64 + ks + quad * 8];
#pragma unroll
      for (int ni = 0; ni < 4; ni++)
        bfr[ni] = *(const bf16x8*)&Bs[(ntoff[ni] + l16) * 64 + ks + quad * 8];
#pragma unroll
      for (int mi = 0; mi < 4; mi++)
#pragma unroll
        for (int ni = 0; ni < 4; ni++)
          acc[mi][ni] = __builtin_amdgcn_mfma_f32_16x16x32_bf16(
              af[mi], bfr[ni], acc[mi][ni], 0, 0, 0);
    }
    __syncthreads();
  }

  float bv[4];
#pragma unroll
  for (int ni = 0; ni < 4; ni++)
    bv[ni] = bias[(head * 3 + 2) * 128 + ntoff[ni] + l16];
#pragma unroll
  for (int mi = 0; mi < 4; mi++) {
#pragma unroll
    for (int ni = 0; ni < 4; ni++) {
      int d = ntoff[ni] + l16;
#pragma unroll
      for (int reg = 0; reg < 4; reg++) {
        int r = rowA0 + wm + mi * 16 + quad * 4 + reg;
        int s = r >> 1, b = r & 1;
        Vt[((size_t)(b * NH + head) * HD + d) * SEQ + s] =
            f2bf(acc[mi][ni][reg] + bv[ni]);
      }
    }
  }
}

// ---- flash attention: single-buffer staging (R11) + split-K for qt>=9 ------
// work table (desc tile count): kh=2 -> unsplit; kh=0/1 -> half of qt+1 tiles
__constant__ int qtA[23] = {8, 15, 15, 7, 14, 14, 13, 13, 6, 12, 12, 11,
                            11, 5, 10, 10, 9, 9, 4, 3, 2, 1, 0};
__constant__ int khA[23] = {2, 0, 1, 2, 0, 1, 0, 1, 2, 0, 1, 0,
                            1, 2, 0, 1, 0, 1, 2, 2, 2, 2, 2};

__global__ __launch_bounds__(256, 2) void attn(
    const u16* __restrict__ Qw, const u16* __restrict__ Kw,
    const u16* __restrict__ Vt, u16* __restrict__ ctx,
    float* __restrict__ po, float* __restrict__ pml) {
  __shared__ __align__(16) u16 Ks[64 * 128];   // 16384 B, linear+XOR-swz
  __shared__ __align__(16) u16 Vs[128 * 64];   // 16384 B, linear+XOR-swz
  __shared__ __align__(16) u16 Pl[4][32 * 64]; // 16384 B  (= 48 KiB total)

  const int tid = threadIdx.x;
  const int wv = tid >> 6, lane = tid & 63;
  const int quad = lane >> 4, l16 = lane & 15;
  const int bh = blockIdx.y;
  const int b = bh >> 4, h = bh & 15;
  const int item = blockIdx.x;
  const int qt = qtA[item];
  const int kh = khA[item];
  const int t0 = (kh == 2) ? 0 : kh * (qt + 1);
  const int t1 = (kh == 2) ? (2 * qt + 2) : (t0 + qt + 1);
  const int sw = qt * 128 + wv * 32;  // this wave's 32 q-rows
  const size_t bhoff = (size_t)bh * SEQ * HD;

  bf16x8 qf[2][4];
#pragma unroll
  for (int mi = 0; mi < 2; mi++)
#pragma unroll
    for (int kc = 0; kc < 4; kc++)
      qf[mi][kc] = *(const bf16x8*)&Qw[bhoff +
                                       (size_t)(sw + mi * 16 + l16) * HD +
                                       kc * 32 + quad * 8];

  floatx4 o[2][8];
#pragma unroll
  for (int mi = 0; mi < 2; mi++)
#pragma unroll
    for (int ni = 0; ni < 8; ni++) o[mi][ni] = (floatx4){0.f, 0.f, 0.f, 0.f};
  float mst[2][4], lst[2][4];
#pragma unroll
  for (int mi = 0; mi < 2; mi++)
#pragma unroll
    for (int r = 0; r < 4; r++) { mst[mi][r] = -1e30f; lst[mi][r] = 0.f; }

  const float SCL2 = 0.088388347648318447f * 1.442695040888963f;
  const float MSK2 = -10000.0f * 1.442695040888963f;
  const float THR = 8.0f;  // defer-max threshold (log2 domain): P <= 2^8

// stage K/V tile tt (single buffer); src pre-swizzled 16B unit u -> u^(row&7)
#define STAGE(tt)                                                              \
  {                                                                            \
    _Pragma("unroll") for (int i = 0; i < 4; i++) {                            \
      int c = i * 256 + tid;                                                   \
      int rk = c >> 4, uk = c & 15;                                            \
      gl16(&Kw[bhoff + (size_t)((tt) * 64 + rk) * HD + (uk ^ (rk & 7)) * 8],   \
           &Ks[(i * 256 + wv * 64) * 8]);                                      \
      int rv_ = c >> 3, uv = c & 7;                                            \
      gl16(&Vt[bhoff + (size_t)rv_ * SEQ + (tt) * 64 + (uv ^ (rv_ & 7)) * 8],  \
           &Vs[(i * 256 + wv * 64) * 8]);                                      \
    }                                                                          \
  }

  for (int t = t0; t < t1; t++) {
    __syncthreads();  // all waves done reading Ks/Vs of prev tile
    STAGE(t);
    __syncthreads();  // drains vmcnt(0): tiles ready

    const bool active = (t * 64 <= sw + 31);
    if (active) {
      const bool diag = (t * 64 + 63 > sw);  // only tile needing causal mask
      floatx4 sa[2][4];
#pragma unroll
      for (int mi = 0; mi < 2; mi++)
#pragma unroll
        for (int ni = 0; ni < 4; ni++) sa[mi][ni] = (floatx4){0.f, 0.f, 0.f, 0.f};
      __builtin_amdgcn_s_setprio(1);
#pragma unroll
      for (int kc = 0; kc < 4; kc++) {
        bf16x8 kf[4];
#pragma unroll
        for (int ni = 0; ni < 4; ni++)
          kf[ni] = *(const bf16x8*)&Ks[(ni * 16 + l16) * 128 +
                                       (((kc * 4 + quad) ^ (l16 & 7)) * 8)];
#pragma unroll
        for (int mi = 0; mi < 2; mi++)
#pragma unroll
          for (int ni = 0; ni < 4; ni++)
            sa[mi][ni] = __builtin_amdgcn_mfma_f32_16x16x32_bf16(
                qf[mi][kc], kf[ni], sa[mi][ni], 0, 0, 0);
      }
      __builtin_amdgcn_s_setprio(0);

      // online softmax (log2 domain) with defer-max
      float alpha[2][4];
      int anyr = 0;
#pragma unroll
      for (int mi = 0; mi < 2; mi++) {
#pragma unroll
        for (int reg = 0; reg < 4; reg++) {
          const int rr = mi * 16 + quad * 4 + reg;
          const int sq = sw + rr;
          float rv[4];
          if (diag) {
#pragma unroll
            for (int ni = 0; ni < 4; ni++) {
              int sk = t * 64 + ni * 16 + l16;
              float v = sa[mi][ni][reg] * SCL2;
              if (sk > sq) v = MSK2;
              rv[ni] = v;
            }
          } else {
#pragma unroll
            for (int ni = 0; ni < 4; ni++) rv[ni] = sa[mi][ni][reg] * SCL2;
          }
          float rmax = fmaxf(fmaxf(rv[0], rv[1]), fmaxf(rv[2], rv[3]));
          rmax = fmaxf(rmax, __shfl_xor(rmax, 1));
          rmax = fmaxf(rmax, __shfl_xor(rmax, 2));
          rmax = fmaxf(rmax, __shfl_xor(rmax, 4));
          rmax = fmaxf(rmax, __shfl_xor(rmax, 8));
          float al;
          if (__all(rmax <= mst[mi][reg] + THR)) {
            al = 1.0f;  // defer: keep old max, skip rescale
          } else {
            float mn = fmaxf(mst[mi][reg], rmax);
            al = exp2f(mst[mi][reg] - mn);
            mst[mi][reg] = mn;
            anyr = 1;
          }
          const float m0 = mst[mi][reg];
          float rs = 0.f;
#pragma unroll
          for (int ni = 0; ni < 4; ni++) {
            float p = exp2f(rv[ni] - m0);
            rs += p;
            Pl[wv][rr * 64 + ((ni * 16 + l16) ^ ((rr & 7) << 3))] = f2bf(p);
          }
          rs += __shfl_xor(rs, 1);
          rs += __shfl_xor(rs, 2);
          rs += __shfl_xor(rs, 4);
          rs += __shfl_xor(rs, 8);
          lst[mi][reg] = lst[mi][reg] * al + rs;
          alpha[mi][reg] = al;
        }
      }
      if (anyr) {  // wave-uniform: rescale only when some row's max moved
#pragma unroll
        for (int mi = 0; mi < 2; mi++)
#pragma unroll
          for (int ni = 0; ni < 8; ni++)
#pragma unroll
            for (int reg = 0; reg < 4; reg++)
              o[mi][ni][reg] *= alpha[mi][reg];
      }

      // PV: P is wave-private (same-wave ds ordering) -> no barrier
      __builtin_amdgcn_s_setprio(1);
#pragma unroll
      for (int kc = 0; kc < 2; kc++) {
        bf16x8 pf[2];
#pragma unroll
        for (int mi = 0; mi < 2; mi++)
          pf[mi] = *(const bf16x8*)&Pl[wv][(mi * 16 + l16) * 64 +
                                           ((kc * 32 + quad * 8) ^
                                            ((l16 & 7) << 3))];
#pragma unroll
        for (int ni = 0; ni < 8; ni++) {
          bf16x8 vf = *(const bf16x8*)&Vs[(ni * 16 + l16) * 64 +
                                          (((kc * 4 + quad) ^ (l16 & 7)) * 8)];
#pragma unroll
          for (int mi = 0; mi < 2; mi++)
            o[mi][ni] = __builtin_amdgcn_mfma_f32_16x16x32_bf16(
                pf[mi], vf, o[mi][ni], 0, 0, 0);
        }
      }
      __builtin_amdgcn_s_setprio(0);
    }
  }

  if (kh == 2) {
    // unsplit: final 1/l and store ctx [s][b][h*128+d]
#pragma unroll
    for (int mi = 0; mi < 2; mi++) {
#pragma unroll
      for (int reg = 0; reg < 4; reg++) {
        float inv = 1.0f / lst[mi][reg];
        int sq = sw + mi * 16 + quad * 4 + reg;
        size_t rbase = ((size_t)(sq * BATCH + b)) * HID + h * HD;
#pragma unroll
        for (int ni = 0; ni < 8; ni++)
          ctx[rbase + ni * 16 + l16] = f2bf(o[mi][ni][reg] * inv);
      }
    }
  } else {
    // split: write f32 partial o + m/l.  pidx = (bh*7 + qt-9)*2 + kh
    const int pidx = (bh * 7 + (qt - 9)) * 2 + kh;
    float* ob = po + (size_t)pidx * 16384;
#pragma unroll
    for (int mi = 0; mi < 2; mi++) {
#pragma unroll
      for (int reg = 0; reg < 4; reg++) {
        int row = wv * 32 + mi * 16 + quad * 4 + reg;
#pragma unroll
        for (int ni = 0; ni < 8; ni++)
          ob[row * 128 + ni * 16 + l16] = o[mi][ni][reg];
        if (l16 == 0) {
          pml[pidx * 256 + row * 2] = mst[mi][reg];
          pml[pidx * 256 + row * 2 + 1] = lst[mi][reg];
        }
      }
    }
  }
#undef STAGE
}

// ---------------- combine split-K partials -> ctx ---------------------------
__global__ __launch_bounds__(256) void combine(const float* __restrict__ po,
                                               const float* __restrict__ pml,
                                               u16* __restrict__ ctx) {
  const int bh = blockIdx.y;         // 0..31
  const int qi = blockIdx.x;         // 0..6 -> qt = 9+qi
  const int qt = 9 + qi;
  const int b = bh >> 4, h = bh & 15;
  const int p0 = (bh * 7 + qi) * 2;
  const int tid = threadIdx.x;
  const int row = tid >> 1;          // 0..127
  const int d0 = (tid & 1) * 64;
  const float m1 = pml[p0 * 256 + row * 2];
  const float l1 = pml[p0 * 256 + row * 2 + 1];
  const float m2 = pml[(p0 + 1) * 256 + row * 2];
  const float l2 = pml[(p0 + 1) * 256 + row * 2 + 1];
  const float mm = fmaxf(m1, m2);
  const float w1 = exp2f(m1 - mm), w2 = exp2f(m2 - mm);
  const float inv = 1.0f / (l1 * w1 + l2 * w2);
  const float* o1 = po + (size_t)p0 * 16384 + row * 128 + d0;
  const float* o2 = po + (size_t)(p0 + 1) * 16384 + row * 128 + d0;
  const int sq = qt * 128 + row;
  u16* cb = ctx + ((size_t)(sq * BATCH + b)) * HID + h * HD + d0;
#pragma unroll
  for (int j = 0; j < 16; j++) {
    floatx4 a = *(const floatx4*)(o1 + j * 4);
    floatx4 c = *(const floatx4*)(o2 + j * 4);
#pragma unroll
    for (int e = 0; e < 4; e++)
      cb[j * 4 + e] = f2bf((a[e] * w1 + c[e] * w2) * inv);
  }
}

// ---------- dense GEMM (ctx bf16 @ wd bf16, gload_lds both) -> FP32 out -----
__global__ __launch_bounds__(256, 2) void dense_gemm(
    const u16* __restrict__ A, const u16* __restrict__ Wd,
    float* __restrict__ out) {
  __shared__ __align__(16) u16 As[128 * 64];
  __shared__ __align__(16) u16 Bs[128 * 64];
  const int tid = threadIdx.x;
  const int wv = tid >> 6, lane = tid & 63;
  const int quad = lane >> 4, l16 = lane & 15;
  const int bn = blockIdx.x, bm = blockIdx.y;
  const int rowA0 = bm * 128, rowB0 = bn * 128;
  const int wm = (wv >> 1) * 64;
  const int wn = (wv & 1) * 64;
  const int ntoff[4] = {wn, wn + 16, wn + 32, wn + 48};

  const int lrow = wv * 32 + (lane >> 3);
  const int lcol = (lane & 7) * 8;
  const u16* Ag = A + (size_t)(rowA0 + lrow) * HID + lcol;
  const u16* Bg = Wd + (size_t)(rowB0 + lrow) * HID + lcol;
  u16* Al = &As[(wv * 32) * 64];
  u16* Bl = &Bs[(wv * 32) * 64];

  floatx4 acc[4][4];
#pragma unroll
  for (int i = 0; i < 4; i++)
#pragma unroll
    for (int j = 0; j < 4; j++) acc[i][j] = (floatx4){0.f, 0.f, 0.f, 0.f};

  for (int kb = 0; kb < HID; kb += 64) {
#pragma unroll
    for (int j = 0; j < 4; j++) {
      gl16(Ag + (size_t)j * 8 * HID + kb, Al + j * 8 * 64);
      gl16(Bg + (size_t)j * 8 * HID + kb, Bl + j * 8 * 64);
    }
    __syncthreads();
#pragma unroll
    for (int ks = 0; ks < 64; ks += 32) {
      bf16x8 af[4], bfr[4];
#pragma unroll
      for (int mi = 0; mi < 4; mi++)
        af[mi] = *(const bf16x8*)&As[(wm + mi * 16 + l16) * 64 + ks + quad * 8];
#pragma unroll
      for (int ni = 0; ni < 4; ni++)
        bfr[ni] = *(const bf16x8*)&Bs[(ntoff[ni] + l16) * 64 + ks + quad * 8];
#pragma unroll
      for (int mi = 0; mi < 4; mi++)
#pragma unroll
        for (int ni = 0; ni < 4; ni++)
          acc[mi][ni] = __builtin_amdgcn_mfma_f32_16x16x32_bf16(
              af[mi], bfr[ni], acc[mi][ni], 0, 0, 0);
    }
    __syncthreads();
  }

#pragma unroll
  for (int mi = 0; mi < 4; mi++)
#pragma unroll
    for (int reg = 0; reg < 4; reg++) {
      int r = rowA0 + wm + mi * 16 + quad * 4 + reg;
#pragma unroll
      for (int ni = 0; ni < 4; ni++)
        out[(size_t)r * HID + bn * 128 + ntoff[ni] + l16] = acc[mi][ni][reg];
    }
}

// ---------------- bias passthrough (fp32 in -> fp32 out tail) ----------------
__global__ void copy_bias(const float* __restrict__ bd, float* __restrict__ out) {
  int i = blockIdx.x * 256 + threadIdx.x;
  if (i < HID) out[(size_t)SEQ * BATCH * HID + i] = bd[i];
}

extern "C" void kernel_launch(void* const* d_in, const int* in_sizes, int n_in,
                              void* d_out, int out_size, void* d_ws,
                              size_t ws_size, hipStream_t stream) {
  // Resolve inputs BY ELEMENT COUNT (dtype-independent):
  //   hidden 8388608, mask 4194304 (unused, precedes w_dense), w_qkv 12582912,
  //   b_qkv 6144, w_dense 4194304 (LAST match wins), b_dense 2048.
  const float *hidden = nullptr, *w_qkv = nullptr, *b_qkv = nullptr;
  const float *w_dense = nullptr, *b_dense = nullptr;
  for (int i = 0; i < n_in; i++) {
    long s = in_sizes[i];
    if (s == 8388608L) hidden = (const float*)d_in[i];
    else if (s == 12582912L) w_qkv = (const float*)d_in[i];
    else if (s == 6144L) b_qkv = (const float*)d_in[i];
    else if (s == 4194304L) w_dense = (const float*)d_in[i];  // last wins
    else if (s == 2048L) b_dense = (const float*)d_in[i];
  }
  float* out = (float*)d_out;

  // Workspace: 64 MiB, time-multiplexed:
  //   [ 0,16M) Qw                       ... later wd (8M, after attn)
  //   [16,32M) Kw
  //   [32,48M) wb K/Q tiles (dead after qkv_qk) -> Vt (written by qkv_v)
  //   [48,64M) Ah bf16 hidden -> ctx (written by attn/combine)
  // d_out scratch (32.008 MB, dead until dense_gemm):
  //   wvw bf16 V-weight tiles [0,8M)  (dead after qkv_v)
  //   po  f32 o-partials 448*16384 floats = 28.0MB   (attn -> combine)
  //   pml f32 m/l partials 448*256 floats = 0.44MB   (attn -> combine)
  char* ws = (char*)d_ws;
  u16* Qw = (u16*)(ws);                 // [ 0,16M)
  u16* Kw = (u16*)(ws + 16777216ll);    // [16,32M)
  u16* Vt = (u16*)(ws + 33554432ll);    // [32,48M) after qkv_v
  u16* wb = (u16*)(ws + 33554432ll);    // [32,48M) K/Q bf16 tiles
  u16* Ah = (u16*)(ws + 50331648ll);    // [48,64M) bf16 hidden (dead by attn)
  u16* ctx = (u16*)(ws + 50331648ll);   // [48,64M) after attn/combine
  u16* wd = (u16*)(ws);                 // [0,8M) bf16 w_dense (after attn)
  u16* wvw = (u16*)d_out;               // d_out scratch (dead after qkv_v)
  float* po = (float*)d_out;            // o-partials (after qkv_v)
  float* pml = (float*)d_out + 7340032; // m/l partials

  cvt_inputs<<<dim3(10240), dim3(256), 0, stream>>>(w_qkv, hidden, wb, Ah, wvw);
  qkv_qk<<<dim3(32, 32), dim3(256), 0, stream>>>(Ah, wb, b_qkv, Qw, Kw);
  qkv_v<<<dim3(16, 32), dim3(256), 0, stream>>>(Ah, wvw, b_qkv, Vt);
  attn<<<dim3(23, 32), dim3(256), 0, stream>>>(Qw, Kw, Vt, ctx, po, pml);
  combine<<<dim3(7, 32), dim3(256), 0, stream>>>(po, pml, ctx);
  cvt_wd<<<dim3(2048), dim3(256), 0, stream>>>(w_dense, wd);
  dense_gemm<<<dim3(16, 32), dim3(256), 0, stream>>>(ctx, wd, out);
  copy_bias<<<dim3(8), dim3(256), 0, stream>>>(b_dense, out);
}

// Round 7
// 469.482 us; speedup vs baseline: 1.0372x; 1.0372x over previous
//
#include <hip/hip_runtime.h>
#include <cstdint>
#include <math.h>

// ---------------------------------------------------------------------------
// ParallelAttention (GPT-NeoX style), MI355X gfx950.
//   SEQ=2048 BATCH=2 HID=2048 NH=16 HD=128, causal mask, RoPE full head dim.
// INTERFACE (established R0-R7): fp32 inputs, fp32 output, inputs resolved by
//   element count (w_dense = LAST 4194304 match; mask unused).
// R9: GEMMs on m97 structure (bf16 pre-convert + global_load_lds w16).
// R10 FAILED: 512-thr attn + reg ping-pong prefetch -> VGPR spills.
// R11: attn 4-wave + gload_lds K/V (pre-swizzled src + XOR read). 133us.
// R12 FAILED: wvw aliased Vt. R13: dbuf regressed (133->154, m99/m132).
// R14: split-K regressed (133->160: +29MB partial writes, no locality fix).
// R15: R11 attn structure restored + XCD-LOCALITY swizzle:
//   - grid linear wgid%8 = XCD (m09). Old mapping put every bh on every XCD
//     -> each XCD's private L2 re-fetched all K/V (FETCH 110MB vs 48MB
//     unique). New bijection wgid = (bh&7) + 8*((bh>>3)*16 + x) pins each
//     bh's 16 blocks to XCD bh%8; 4 bh/XCD -> 4MB K/V, L2-resident (T1).
//   - balanced pairing kept: qt = ((bh_hi>>1)&1) ? 15-x : x (34 tiles/CU).
//   - riders kept (R13/R14-proven): defer-max, diag-skip, log2 softmax,
//     P stride-64 XOR swizzle, setprio. 48KiB LDS.
//   - qkv_v pure gload_lds (wvw bf16 in d_out scratch; R14-proven).
// MFMA 16x16x32 bf16: A/B row=lane&15, k=(lane>>4)*8+j; C/D col=lane&15,
//   row=(lane>>4)*4+reg (verified m89/m91).
// global_load_lds: LDS dest is wave-uniform base + lane*16B (m104/m108) --
//   LDS must be LINEAR, source address is per-lane (pre-swizzle there).
// ---------------------------------------------------------------------------

typedef unsigned short u16;
typedef __bf16 bf16x8 __attribute__((ext_vector_type(8)));
typedef float floatx4 __attribute__((ext_vector_type(4)));

#define SEQ 2048
#define BATCH 2
#define HID 2048
#define NH 16
#define HD 128

__device__ __forceinline__ u16 f2bf(float f) {
  union { float f; uint32_t u; } v; v.f = f;
  uint32_t u = v.u;
  return (u16)((u + 0x7FFFu + ((u >> 16) & 1u)) >> 16);
}

// pack 8 fp32 -> 8 bf16 (RNE) and store 16B
__device__ __forceinline__ void st8_bf16(u16* dst, const float* s) {
  uint32_t pk[4];
#pragma unroll
  for (int j = 0; j < 4; j++)
    pk[j] = (uint32_t)f2bf(s[2 * j]) | ((uint32_t)f2bf(s[2 * j + 1]) << 16);
  *(uint4*)dst = make_uint4(pk[0], pk[1], pk[2], pk[3]);
}

// async global->LDS, 16B per lane; lds base must be wave-uniform
__device__ __forceinline__ void gl16(const u16* g, u16* l) {
  __builtin_amdgcn_global_load_lds(
      (const __attribute__((address_space(1))) void*)g,
      (__attribute__((address_space(3))) void*)l, 16, 0, 0);
}

// ------- input conversion: w_qkv K/Q tiles, hidden, V tiles -> bf16 ---------
// wb tile order: [K head 0..15][Q head 0..15]; src K h = 3h+1, Q h = 3h.
// V tiles (blk >= 8192) -> wvw (lives in d_out scratch), src h = 3h+2.
__global__ __launch_bounds__(256) void cvt_inputs(
    const float* __restrict__ W, const float* __restrict__ Hid,
    u16* __restrict__ wb, u16* __restrict__ Ah, u16* __restrict__ wvw) {
  const int blk = blockIdx.x;
  const int c0 = threadIdx.x * 8;
  const float* src;
  u16* dst;
  if (blk < 4096) {
    int dt = blk >> 7, r = blk & 127;
    int srow = (dt < 16) ? ((dt * 3 + 1) * 128 + r) : (((dt - 16) * 3) * 128 + r);
    src = W + (size_t)srow * HID;
    dst = wb + (size_t)blk * HID;
  } else if (blk < 8192) {
    int r = blk - 4096;
    src = Hid + (size_t)r * HID;
    dst = Ah + (size_t)r * HID;
  } else {
    int v = blk - 8192;  // 0..2047
    int h = v >> 7, r = v & 127;
    src = W + (size_t)((h * 3 + 2) * 128 + r) * HID;
    dst = wvw + (size_t)v * HID;
  }
  float t[8];
  *(floatx4*)&t[0] = *(const floatx4*)(src + c0);
  *(floatx4*)&t[4] = *(const floatx4*)(src + c0 + 4);
  st8_bf16(dst + c0, t);
}

// ---------------- w_dense fp32 -> bf16 --------------------------------------
__global__ __launch_bounds__(256) void cvt_wd(const float* __restrict__ W,
                                              u16* __restrict__ wd) {
  const int r = blockIdx.x;
  const int c0 = threadIdx.x * 8;
  float t[8];
  const float* src = W + (size_t)r * HID;
  *(floatx4*)&t[0] = *(const floatx4*)(src + c0);
  *(floatx4*)&t[4] = *(const floatx4*)(src + c0 + 4);
  st8_bf16(wd + (size_t)r * HID + c0, t);
}

// ---------------- QK projection: bf16 @ bf16, gload_lds both operands -------
__global__ __launch_bounds__(256, 2) void qkv_qk(
    const u16* __restrict__ Ah, const u16* __restrict__ wb,
    const float* __restrict__ bias, u16* __restrict__ Qw,
    u16* __restrict__ Kw) {
  __shared__ __align__(16) u16 As[128 * 64];
  __shared__ __align__(16) u16 Bs[128 * 64];
  const int tid = threadIdx.x;
  const int wv = tid >> 6, lane = tid & 63;
  const int quad = lane >> 4, l16 = lane & 15;
  const int wt = blockIdx.x;  // 0..15 = K head wt, 16..31 = Q head wt-16
  const int bm = blockIdx.y;
  const int rowA0 = bm * 128;
  const int wm = (wv >> 1) * 64;
  const int wn = (wv & 1) * 32;
  const int ntoff[4] = {wn, wn + 16, wn + 64, wn + 80};

  const int lrow = wv * 32 + (lane >> 3);
  const int lcol = (lane & 7) * 8;
  const u16* Ag = Ah + (size_t)(rowA0 + lrow) * HID + lcol;
  const u16* Bg = wb + ((size_t)wt * 128 + lrow) * HID + lcol;
  u16* Al = &As[(wv * 32) * 64];  // wave-uniform
  u16* Bl = &Bs[(wv * 32) * 64];

  floatx4 acc[4][4];
#pragma unroll
  for (int i = 0; i < 4; i++)
#pragma unroll
    for (int j = 0; j < 4; j++) acc[i][j] = (floatx4){0.f, 0.f, 0.f, 0.f};

  for (int kb = 0; kb < HID; kb += 64) {
#pragma unroll
    for (int j = 0; j < 4; j++) {
      gl16(Ag + (size_t)j * 8 * HID + kb, Al + j * 8 * 64);
      gl16(Bg + (size_t)j * 8 * HID + kb, Bl + j * 8 * 64);
    }
    __syncthreads();  // drains vmcnt(0): LDS tiles ready
#pragma unroll
    for (int ks = 0; ks < 64; ks += 32) {
      bf16x8 af[4], bfr[4];
#pragma unroll
      for (int mi = 0; mi < 4; mi++)
        af[mi] = *(const bf16x8*)&As[(wm + mi * 16 + l16) * 64 + ks + quad * 8];
#pragma unroll
      for (int ni = 0; ni < 4; ni++)
        bfr[ni] = *(const bf16x8*)&Bs[(ntoff[ni] + l16) * 64 + ks + quad * 8];
#pragma unroll
      for (int mi = 0; mi < 4; mi++)
#pragma unroll
        for (int ni = 0; ni < 4; ni++)
          acc[mi][ni] = __builtin_amdgcn_mfma_f32_16x16x32_bf16(
              af[mi], bfr[ni], acc[mi][ni], 0, 0, 0);
    }
    __syncthreads();  // all waves done reading before next gload_lds overwrite
  }

  // epilogue: bias + RoPE (inline cos/sin)
  const int seg = (wt < 16) ? 1 : 0;  // 1=K, 0=Q
  const int head = wt & 15;
  u16* dst = seg ? Kw : Qw;
  float bv[4];
#pragma unroll
  for (int ni = 0; ni < 4; ni++)
    bv[ni] = bias[(head * 3 + seg) * 128 + ntoff[ni] + l16];
  const float RC = 0.20762050593045951f;  // log2(10000)/64
  const float f0 = exp2f(-(float)(wn + l16) * RC);
  const float f1 = exp2f(-(float)(wn + 16 + l16) * RC);

#pragma unroll
  for (int mi = 0; mi < 4; mi++) {
#pragma unroll
    for (int reg = 0; reg < 4; reg++) {
      int r = rowA0 + wm + mi * 16 + quad * 4 + reg;
      int s = r >> 1, b = r & 1;
      size_t base = ((size_t)(b * NH + head) * SEQ + s) * HD;
      float sv, cv;
      sincosf((float)s * f0, &sv, &cv);
      {
        float lo = acc[mi][0][reg] + bv[0];
        float hi = acc[mi][2][reg] + bv[2];
        dst[base + wn + l16] = f2bf(lo * cv - hi * sv);
        dst[base + wn + l16 + 64] = f2bf(hi * cv + lo * sv);
      }
      sincosf((float)s * f1, &sv, &cv);
      {
        float lo = acc[mi][1][reg] + bv[1];
        float hi = acc[mi][3][reg] + bv[3];
        dst[base + wn + 16 + l16] = f2bf(lo * cv - hi * sv);
        dst[base + wn + 16 + l16 + 64] = f2bf(hi * cv + lo * sv);
      }
    }
  }
}

// ---------------- V projection: pure gload_lds (wvw in d_out scratch) -------
__global__ __launch_bounds__(256, 2) void qkv_v(
    const u16* __restrict__ Ah, const u16* __restrict__ wvw,
    const float* __restrict__ bias, u16* __restrict__ Vt) {
  __shared__ __align__(16) u16 As[128 * 64];
  __shared__ __align__(16) u16 Bs[128 * 64];
  const int tid = threadIdx.x;
  const int wv = tid >> 6, lane = tid & 63;
  const int quad = lane >> 4, l16 = lane & 15;
  const int head = blockIdx.x;  // 0..15
  const int bm = blockIdx.y;
  const int rowA0 = bm * 128;
  const int wm = (wv >> 1) * 64;
  const int wn = (wv & 1) * 32;
  const int ntoff[4] = {wn, wn + 16, wn + 64, wn + 80};

  const int lrow = wv * 32 + (lane >> 3);
  const int lcol = (lane & 7) * 8;
  const u16* Ag = Ah + (size_t)(rowA0 + lrow) * HID + lcol;
  const u16* Bg = wvw + ((size_t)head * 128 + lrow) * HID + lcol;
  u16* Al = &As[(wv * 32) * 64];
  u16* Bl = &Bs[(wv * 32) * 64];

  floatx4 acc[4][4];
#pragma unroll
  for (int i = 0; i < 4; i++)
#pragma unroll
    for (int j = 0; j < 4; j++) acc[i][j] = (floatx4){0.f, 0.f, 0.f, 0.f};

  for (int kb = 0; kb < HID; kb += 64) {
#pragma unroll
    for (int j = 0; j < 4; j++) {
      gl16(Ag + (size_t)j * 8 * HID + kb, Al + j * 8 * 64);
      gl16(Bg + (size_t)j * 8 * HID + kb, Bl + j * 8 * 64);
    }
    __syncthreads();
#pragma unroll
    for (int ks = 0; ks < 64; ks += 32) {
      bf16x8 af[4], bfr[4];
#pragma unroll
      for (int mi = 0; mi < 4; mi++)
        af[mi] = *(const bf16x8*)&As[(wm + mi * 16 + l16) * 64 + ks + quad * 8];
#pragma unroll
      for (int ni = 0; ni < 4; ni++)
        bfr[ni] = *(const bf16x8*)&Bs[(ntoff[ni] + l16) * 64 + ks + quad * 8];
#pragma unroll
      for (int mi = 0; mi < 4; mi++)
#pragma unroll
        for (int ni = 0; ni < 4; ni++)
          acc[mi][ni] = __builtin_amdgcn_mfma_f32_16x16x32_bf16(
              af[mi], bfr[ni], acc[mi][ni], 0, 0, 0);
    }
    __syncthreads();
  }

  float bv[4];
#pragma unroll
  for (int ni = 0; ni < 4; ni++)
    bv[ni] = bias[(head * 3 + 2) * 128 + ntoff[ni] + l16];
#pragma unroll
  for (int mi = 0; mi < 4; mi++) {
#pragma unroll
    for (int ni = 0; ni < 4; ni++) {
      int d = ntoff[ni] + l16;
#pragma unroll
      for (int reg = 0; reg < 4; reg++) {
        int r = rowA0 + wm + mi * 16 + quad * 4 + reg;
        int s = r >> 1, b = r & 1;
        Vt[((size_t)(b * NH + head) * HD + d) * SEQ + s] =
            f2bf(acc[mi][ni][reg] + bv[ni]);
      }
    }
  }
}

// ---- flash attention: R11 structure + XCD-locality swizzle -----------------
__global__ __launch_bounds__(256, 2) void attn(
    const u16* __restrict__ Qw, const u16* __restrict__ Kw,
    const u16* __restrict__ Vt, u16* __restrict__ ctx) {
  __shared__ __align__(16) u16 Ks[64 * 128];   // 16384 B, linear+XOR-swz
  __shared__ __align__(16) u16 Vs[128 * 64];   // 16384 B, linear+XOR-swz
  __shared__ __align__(16) u16 Pl[4][32 * 64]; // 16384 B  (= 48 KiB total)

  const int tid = threadIdx.x;
  const int wv = tid >> 6, lane = tid & 63;
  const int quad = lane >> 4, l16 = lane & 15;

  // XCD-locality decode: wgid%8 = XCD (m09). wgid = (bh&7) + 8*((bh>>3)*16+x)
  // -> all 16 blocks of a bh land on XCD bh%8 (4 bh per XCD, K/V L2-resident).
  // Balanced pairing: qt = ((bh_hi>>1)&1) ? 15-x : x -> 34 tiles per CU pair.
  const int lin = blockIdx.y * gridDim.x + blockIdx.x;
  const int xcdsel = lin & 7;
  const int k = lin >> 3;        // 0..63
  const int bh_hi = k >> 4;      // 0..3
  const int x = k & 15;
  const int bh = (bh_hi << 3) | xcdsel;
  const int qt = ((bh_hi >> 1) & 1) ? (15 - x) : x;

  const int b = bh >> 4, h = bh & 15;
  const int sw = qt * 128 + wv * 32;  // this wave's 32 q-rows
  const size_t bhoff = (size_t)bh * SEQ * HD;

  bf16x8 qf[2][4];
#pragma unroll
  for (int mi = 0; mi < 2; mi++)
#pragma unroll
    for (int kc = 0; kc < 4; kc++)
      qf[mi][kc] = *(const bf16x8*)&Qw[bhoff +
                                       (size_t)(sw + mi * 16 + l16) * HD +
                                       kc * 32 + quad * 8];

  floatx4 o[2][8];
#pragma unroll
  for (int mi = 0; mi < 2; mi++)
#pragma unroll
    for (int ni = 0; ni < 8; ni++) o[mi][ni] = (floatx4){0.f, 0.f, 0.f, 0.f};
  float mst[2][4], lst[2][4];
#pragma unroll
  for (int mi = 0; mi < 2; mi++)
#pragma unroll
    for (int r = 0; r < 4; r++) { mst[mi][r] = -1e30f; lst[mi][r] = 0.f; }

  const int nt = qt * 2 + 2;
  const float SCL2 = 0.088388347648318447f * 1.442695040888963f;
  const float MSK2 = -10000.0f * 1.442695040888963f;
  const float THR = 8.0f;  // defer-max threshold (log2 domain): P <= 2^8

// stage K/V tile tt (single buffer); src pre-swizzled 16B unit u -> u^(row&7)
#define STAGE(tt)                                                              \
  {                                                                            \
    _Pragma("unroll") for (int i = 0; i < 4; i++) {                            \
      int c = i * 256 + tid;                                                   \
      int rk = c >> 4, uk = c & 15;                                            \
      gl16(&Kw[bhoff + (size_t)((tt) * 64 + rk) * HD + (uk ^ (rk & 7)) * 8],   \
           &Ks[(i * 256 + wv * 64) * 8]);                                      \
      int rv_ = c >> 3, uv = c & 7;                                            \
      gl16(&Vt[bhoff + (size_t)rv_ * SEQ + (tt) * 64 + (uv ^ (rv_ & 7)) * 8],  \
           &Vs[(i * 256 + wv * 64) * 8]);                                      \
    }                                                                          \
  }

  for (int t = 0; t < nt; t++) {
    __syncthreads();  // all waves done reading Ks/Vs of prev tile
    STAGE(t);
    __syncthreads();  // drains vmcnt(0): tiles ready

    const bool active = (t * 64 <= sw + 31);
    if (active) {
      const bool diag = (t * 64 + 63 > sw);  // only tile needing causal mask
      floatx4 sa[2][4];
#pragma unroll
      for (int mi = 0; mi < 2; mi++)
#pragma unroll
        for (int ni = 0; ni < 4; ni++) sa[mi][ni] = (floatx4){0.f, 0.f, 0.f, 0.f};
      __builtin_amdgcn_s_setprio(1);
#pragma unroll
      for (int kc = 0; kc < 4; kc++) {
        bf16x8 kf[4];
#pragma unroll
        for (int ni = 0; ni < 4; ni++)
          kf[ni] = *(const bf16x8*)&Ks[(ni * 16 + l16) * 128 +
                                       (((kc * 4 + quad) ^ (l16 & 7)) * 8)];
#pragma unroll
        for (int mi = 0; mi < 2; mi++)
#pragma unroll
          for (int ni = 0; ni < 4; ni++)
            sa[mi][ni] = __builtin_amdgcn_mfma_f32_16x16x32_bf16(
                qf[mi][kc], kf[ni], sa[mi][ni], 0, 0, 0);
      }
      __builtin_amdgcn_s_setprio(0);

      // online softmax (log2 domain) with defer-max
      float alpha[2][4];
      int anyr = 0;
#pragma unroll
      for (int mi = 0; mi < 2; mi++) {
#pragma unroll
        for (int reg = 0; reg < 4; reg++) {
          const int rr = mi * 16 + quad * 4 + reg;
          const int sq = sw + rr;
          float rv[4];
          if (diag) {
#pragma unroll
            for (int ni = 0; ni < 4; ni++) {
              int sk = t * 64 + ni * 16 + l16;
              float v = sa[mi][ni][reg] * SCL2;
              if (sk > sq) v = MSK2;
              rv[ni] = v;
            }
          } else {
#pragma unroll
            for (int ni = 0; ni < 4; ni++) rv[ni] = sa[mi][ni][reg] * SCL2;
          }
          float rmax = fmaxf(fmaxf(rv[0], rv[1]), fmaxf(rv[2], rv[3]));
          rmax = fmaxf(rmax, __shfl_xor(rmax, 1));
          rmax = fmaxf(rmax, __shfl_xor(rmax, 2));
          rmax = fmaxf(rmax, __shfl_xor(rmax, 4));
          rmax = fmaxf(rmax, __shfl_xor(rmax, 8));
          float al;
          if (__all(rmax <= mst[mi][reg] + THR)) {
            al = 1.0f;  // defer: keep old max, skip rescale
          } else {
            float mn = fmaxf(mst[mi][reg], rmax);
            al = exp2f(mst[mi][reg] - mn);
            mst[mi][reg] = mn;
            anyr = 1;
          }
          const float m0 = mst[mi][reg];
          float rs = 0.f;
#pragma unroll
          for (int ni = 0; ni < 4; ni++) {
            float p = exp2f(rv[ni] - m0);
            rs += p;
            Pl[wv][rr * 64 + ((ni * 16 + l16) ^ ((rr & 7) << 3))] = f2bf(p);
          }
          rs += __shfl_xor(rs, 1);
          rs += __shfl_xor(rs, 2);
          rs += __shfl_xor(rs, 4);
          rs += __shfl_xor(rs, 8);
          lst[mi][reg] = lst[mi][reg] * al + rs;
          alpha[mi][reg] = al;
        }
      }
      if (anyr) {  // wave-uniform: rescale only when some row's max moved
#pragma unroll
        for (int mi = 0; mi < 2; mi++)
#pragma unroll
          for (int ni = 0; ni < 8; ni++)
#pragma unroll
            for (int reg = 0; reg < 4; reg++)
              o[mi][ni][reg] *= alpha[mi][reg];
      }

      // PV: P is wave-private (same-wave ds ordering) -> no barrier
      __builtin_amdgcn_s_setprio(1);
#pragma unroll
      for (int kc = 0; kc < 2; kc++) {
        bf16x8 pf[2];
#pragma unroll
        for (int mi = 0; mi < 2; mi++)
          pf[mi] = *(const bf16x8*)&Pl[wv][(mi * 16 + l16) * 64 +
                                           ((kc * 32 + quad * 8) ^
                                            ((l16 & 7) << 3))];
#pragma unroll
        for (int ni = 0; ni < 8; ni++) {
          bf16x8 vf = *(const bf16x8*)&Vs[(ni * 16 + l16) * 64 +
                                          (((kc * 4 + quad) ^ (l16 & 7)) * 8)];
#pragma unroll
          for (int mi = 0; mi < 2; mi++)
            o[mi][ni] = __builtin_amdgcn_mfma_f32_16x16x32_bf16(
                pf[mi], vf, o[mi][ni], 0, 0, 0);
        }
      }
      __builtin_amdgcn_s_setprio(0);
    }
  }

  // final 1/l and store ctx [s][b][h*128+d]
#pragma unroll
  for (int mi = 0; mi < 2; mi++) {
#pragma unroll
    for (int reg = 0; reg < 4; reg++) {
      float inv = 1.0f / lst[mi][reg];
      int sq = sw + mi * 16 + quad * 4 + reg;
      size_t rbase = ((size_t)(sq * BATCH + b)) * HID + h * HD;
#pragma unroll
      for (int ni = 0; ni < 8; ni++)
        ctx[rbase + ni * 16 + l16] = f2bf(o[mi][ni][reg] * inv);
    }
  }
#undef STAGE
}

// ---------- dense GEMM (ctx bf16 @ wd bf16, gload_lds both) -> FP32 out -----
__global__ __launch_bounds__(256, 2) void dense_gemm(
    const u16* __restrict__ A, const u16* __restrict__ Wd,
    float* __restrict__ out) {
  __shared__ __align__(16) u16 As[128 * 64];
  __shared__ __align__(16) u16 Bs[128 * 64];
  const int tid = threadIdx.x;
  const int wv = tid >> 6, lane = tid & 63;
  const int quad = lane >> 4, l16 = lane & 15;
  const int bn = blockIdx.x, bm = blockIdx.y;
  const int rowA0 = bm * 128, rowB0 = bn * 128;
  const int wm = (wv >> 1) * 64;
  const int wn = (wv & 1) * 64;
  const int ntoff[4] = {wn, wn + 16, wn + 32, wn + 48};

  const int lrow = wv * 32 + (lane >> 3);
  const int lcol = (lane & 7) * 8;
  const u16* Ag = A + (size_t)(rowA0 + lrow) * HID + lcol;
  const u16* Bg = Wd + (size_t)(rowB0 + lrow) * HID + lcol;
  u16* Al = &As[(wv * 32) * 64];
  u16* Bl = &Bs[(wv * 32) * 64];

  floatx4 acc[4][4];
#pragma unroll
  for (int i = 0; i < 4; i++)
#pragma unroll
    for (int j = 0; j < 4; j++) acc[i][j] = (floatx4){0.f, 0.f, 0.f, 0.f};

  for (int kb = 0; kb < HID; kb += 64) {
#pragma unroll
    for (int j = 0; j < 4; j++) {
      gl16(Ag + (size_t)j * 8 * HID + kb, Al + j * 8 * 64);
      gl16(Bg + (size_t)j * 8 * HID + kb, Bl + j * 8 * 64);
    }
    __syncthreads();
#pragma unroll
    for (int ks = 0; ks < 64; ks += 32) {
      bf16x8 af[4], bfr[4];
#pragma unroll
      for (int mi = 0; mi < 4; mi++)
        af[mi] = *(const bf16x8*)&As[(wm + mi * 16 + l16) * 64 + ks + quad * 8];
#pragma unroll
      for (int ni = 0; ni < 4; ni++)
        bfr[ni] = *(const bf16x8*)&Bs[(ntoff[ni] + l16) * 64 + ks + quad * 8];
#pragma unroll
      for (int mi = 0; mi < 4; mi++)
#pragma unroll
        for (int ni = 0; ni < 4; ni++)
          acc[mi][ni] = __builtin_amdgcn_mfma_f32_16x16x32_bf16(
              af[mi], bfr[ni], acc[mi][ni], 0, 0, 0);
    }
    __syncthreads();
  }

#pragma unroll
  for (int mi = 0; mi < 4; mi++)
#pragma unroll
    for (int reg = 0; reg < 4; reg++) {
      int r = rowA0 + wm + mi * 16 + quad * 4 + reg;
#pragma unroll
      for (int ni = 0; ni < 4; ni++)
        out[(size_t)r * HID + bn * 128 + ntoff[ni] + l16] = acc[mi][ni][reg];
    }
}

// ---------------- bias passthrough (fp32 in -> fp32 out tail) ----------------
__global__ void copy_bias(const float* __restrict__ bd, float* __restrict__ out) {
  int i = blockIdx.x * 256 + threadIdx.x;
  if (i < HID) out[(size_t)SEQ * BATCH * HID + i] = bd[i];
}

extern "C" void kernel_launch(void* const* d_in, const int* in_sizes, int n_in,
                              void* d_out, int out_size, void* d_ws,
                              size_t ws_size, hipStream_t stream) {
  // Resolve inputs BY ELEMENT COUNT (dtype-independent):
  //   hidden 8388608, mask 4194304 (unused, precedes w_dense), w_qkv 12582912,
  //   b_qkv 6144, w_dense 4194304 (LAST match wins), b_dense 2048.
  const float *hidden = nullptr, *w_qkv = nullptr, *b_qkv = nullptr;
  const float *w_dense = nullptr, *b_dense = nullptr;
  for (int i = 0; i < n_in; i++) {
    long s = in_sizes[i];
    if (s == 8388608L) hidden = (const float*)d_in[i];
    else if (s == 12582912L) w_qkv = (const float*)d_in[i];
    else if (s == 6144L) b_qkv = (const float*)d_in[i];
    else if (s == 4194304L) w_dense = (const float*)d_in[i];  // last wins
    else if (s == 2048L) b_dense = (const float*)d_in[i];
  }
  float* out = (float*)d_out;

  // Workspace: 64 MiB, time-multiplexed:
  //   [ 0,16M) Qw                       ... later wd (8M, after attn)
  //   [16,32M) Kw
  //   [32,48M) wb K/Q tiles (dead after qkv_qk) -> Vt (written by qkv_v)
  //   [48,64M) Ah bf16 hidden -> ctx (written by attn)
  // wvw (bf16 V-weight tiles, 8M) lives in d_out scratch (dead until
  // dense_gemm overwrites it).
  char* ws = (char*)d_ws;
  u16* Qw = (u16*)(ws);                 // [ 0,16M)
  u16* Kw = (u16*)(ws + 16777216ll);    // [16,32M)
  u16* Vt = (u16*)(ws + 33554432ll);    // [32,48M) after qkv_v
  u16* wb = (u16*)(ws + 33554432ll);    // [32,48M) K/Q bf16 tiles
  u16* Ah = (u16*)(ws + 50331648ll);    // [48,64M) bf16 hidden (dead by attn)
  u16* ctx = (u16*)(ws + 50331648ll);   // [48,64M) after attn
  u16* wd = (u16*)(ws);                 // [0,8M) bf16 w_dense (after attn)
  u16* wvw = (u16*)d_out;               // d_out scratch (dead after qkv_v)

  cvt_inputs<<<dim3(10240), dim3(256), 0, stream>>>(w_qkv, hidden, wb, Ah, wvw);
  qkv_qk<<<dim3(32, 32), dim3(256), 0, stream>>>(Ah, wb, b_qkv, Qw, Kw);
  qkv_v<<<dim3(16, 32), dim3(256), 0, stream>>>(Ah, wvw, b_qkv, Vt);
  attn<<<dim3(16, 32), dim3(256), 0, stream>>>(Qw, Kw, Vt, ctx);
  cvt_wd<<<dim3(2048), dim3(256), 0, stream>>>(w_dense, wd);
  dense_gemm<<<dim3(16, 32), dim3(256), 0, stream>>>(ctx, wd, out);
  copy_bias<<<dim3(8), dim3(256), 0, stream>>>(b_dense, out);
}

// Round 8
// 452.670 us; speedup vs baseline: 1.0757x; 1.0371x over previous
//
#include <hip/hip_runtime.h>
#include <cstdint>
#include <math.h>

// ---------------------------------------------------------------------------
// ParallelAttention (GPT-NeoX style), MI355X gfx950.
//   SEQ=2048 BATCH=2 HID=2048 NH=16 HD=128, causal mask, RoPE full head dim.
// INTERFACE (established R0-R7): fp32 inputs, fp32 output, inputs resolved by
//   element count (w_dense = LAST 4194304 match; mask unused).
// R9: GEMMs on m97 structure (bf16 pre-convert + global_load_lds w16).
// R10 FAILED: 512-thr attn + reg ping-pong prefetch -> VGPR spills.
// R11: attn 4-wave + gload_lds K/V (pre-swizzled src + XOR read). 133us.
// R12 FAILED: wvw aliased Vt. R13: dbuf+riders 154. R14: split-K+riders 160.
// R15: XCD swizzle+riders: FETCH 110->25MB (locality theory CONFIRMED) but
//   attn 153us. Cross-round A/B: R13/R14/R15 all ~153-160 with riders across
//   3 DIFFERENT structures; R11=133 without. Riders (defer-max __all chains +
//   diag branch duplication in 8x-unrolled softmax) cost ~20us, swamping
//   their catalog gains. VGPR 120->128 corroborates.
// R16: attn inner loop = EXACTLY R11 (always-mask, always-rescale, P
//   stride-72, no data-dependent branches). Kept proven deltas only:
//   - XCD-locality swizzle (R15-verified: K/V L2-resident, FETCH 25MB).
//   - qkv_v pure gload_lds + wvw in d_out scratch (R14/R15-proven).
// MFMA 16x16x32 bf16: A/B row=lane&15, k=(lane>>4)*8+j; C/D col=lane&15,
//   row=(lane>>4)*4+reg (verified m89/m91).
// global_load_lds: LDS dest is wave-uniform base + lane*16B (m104/m108) --
//   LDS must be LINEAR, source address is per-lane (pre-swizzle there).
// ---------------------------------------------------------------------------

typedef unsigned short u16;
typedef __bf16 bf16x8 __attribute__((ext_vector_type(8)));
typedef float floatx4 __attribute__((ext_vector_type(4)));

#define SEQ 2048
#define BATCH 2
#define HID 2048
#define NH 16
#define HD 128

__device__ __forceinline__ u16 f2bf(float f) {
  union { float f; uint32_t u; } v; v.f = f;
  uint32_t u = v.u;
  return (u16)((u + 0x7FFFu + ((u >> 16) & 1u)) >> 16);
}

// pack 8 fp32 -> 8 bf16 (RNE) and store 16B
__device__ __forceinline__ void st8_bf16(u16* dst, const float* s) {
  uint32_t pk[4];
#pragma unroll
  for (int j = 0; j < 4; j++)
    pk[j] = (uint32_t)f2bf(s[2 * j]) | ((uint32_t)f2bf(s[2 * j + 1]) << 16);
  *(uint4*)dst = make_uint4(pk[0], pk[1], pk[2], pk[3]);
}

// async global->LDS, 16B per lane; lds base must be wave-uniform
__device__ __forceinline__ void gl16(const u16* g, u16* l) {
  __builtin_amdgcn_global_load_lds(
      (const __attribute__((address_space(1))) void*)g,
      (__attribute__((address_space(3))) void*)l, 16, 0, 0);
}

// ------- input conversion: w_qkv K/Q tiles, hidden, V tiles -> bf16 ---------
// wb tile order: [K head 0..15][Q head 0..15]; src K h = 3h+1, Q h = 3h.
// V tiles (blk >= 8192) -> wvw (lives in d_out scratch), src h = 3h+2.
__global__ __launch_bounds__(256) void cvt_inputs(
    const float* __restrict__ W, const float* __restrict__ Hid,
    u16* __restrict__ wb, u16* __restrict__ Ah, u16* __restrict__ wvw) {
  const int blk = blockIdx.x;
  const int c0 = threadIdx.x * 8;
  const float* src;
  u16* dst;
  if (blk < 4096) {
    int dt = blk >> 7, r = blk & 127;
    int srow = (dt < 16) ? ((dt * 3 + 1) * 128 + r) : (((dt - 16) * 3) * 128 + r);
    src = W + (size_t)srow * HID;
    dst = wb + (size_t)blk * HID;
  } else if (blk < 8192) {
    int r = blk - 4096;
    src = Hid + (size_t)r * HID;
    dst = Ah + (size_t)r * HID;
  } else {
    int v = blk - 8192;  // 0..2047
    int h = v >> 7, r = v & 127;
    src = W + (size_t)((h * 3 + 2) * 128 + r) * HID;
    dst = wvw + (size_t)v * HID;
  }
  float t[8];
  *(floatx4*)&t[0] = *(const floatx4*)(src + c0);
  *(floatx4*)&t[4] = *(const floatx4*)(src + c0 + 4);
  st8_bf16(dst + c0, t);
}

// ---------------- w_dense fp32 -> bf16 --------------------------------------
__global__ __launch_bounds__(256) void cvt_wd(const float* __restrict__ W,
                                              u16* __restrict__ wd) {
  const int r = blockIdx.x;
  const int c0 = threadIdx.x * 8;
  float t[8];
  const float* src = W + (size_t)r * HID;
  *(floatx4*)&t[0] = *(const floatx4*)(src + c0);
  *(floatx4*)&t[4] = *(const floatx4*)(src + c0 + 4);
  st8_bf16(wd + (size_t)r * HID + c0, t);
}

// ---------------- QK projection: bf16 @ bf16, gload_lds both operands -------
__global__ __launch_bounds__(256, 2) void qkv_qk(
    const u16* __restrict__ Ah, const u16* __restrict__ wb,
    const float* __restrict__ bias, u16* __restrict__ Qw,
    u16* __restrict__ Kw) {
  __shared__ __align__(16) u16 As[128 * 64];
  __shared__ __align__(16) u16 Bs[128 * 64];
  const int tid = threadIdx.x;
  const int wv = tid >> 6, lane = tid & 63;
  const int quad = lane >> 4, l16 = lane & 15;
  const int wt = blockIdx.x;  // 0..15 = K head wt, 16..31 = Q head wt-16
  const int bm = blockIdx.y;
  const int rowA0 = bm * 128;
  const int wm = (wv >> 1) * 64;
  const int wn = (wv & 1) * 32;
  const int ntoff[4] = {wn, wn + 16, wn + 64, wn + 80};

  const int lrow = wv * 32 + (lane >> 3);
  const int lcol = (lane & 7) * 8;
  const u16* Ag = Ah + (size_t)(rowA0 + lrow) * HID + lcol;
  const u16* Bg = wb + ((size_t)wt * 128 + lrow) * HID + lcol;
  u16* Al = &As[(wv * 32) * 64];  // wave-uniform
  u16* Bl = &Bs[(wv * 32) * 64];

  floatx4 acc[4][4];
#pragma unroll
  for (int i = 0; i < 4; i++)
#pragma unroll
    for (int j = 0; j < 4; j++) acc[i][j] = (floatx4){0.f, 0.f, 0.f, 0.f};

  for (int kb = 0; kb < HID; kb += 64) {
#pragma unroll
    for (int j = 0; j < 4; j++) {
      gl16(Ag + (size_t)j * 8 * HID + kb, Al + j * 8 * 64);
      gl16(Bg + (size_t)j * 8 * HID + kb, Bl + j * 8 * 64);
    }
    __syncthreads();  // drains vmcnt(0): LDS tiles ready
#pragma unroll
    for (int ks = 0; ks < 64; ks += 32) {
      bf16x8 af[4], bfr[4];
#pragma unroll
      for (int mi = 0; mi < 4; mi++)
        af[mi] = *(const bf16x8*)&As[(wm + mi * 16 + l16) * 64 + ks + quad * 8];
#pragma unroll
      for (int ni = 0; ni < 4; ni++)
        bfr[ni] = *(const bf16x8*)&Bs[(ntoff[ni] + l16) * 64 + ks + quad * 8];
#pragma unroll
      for (int mi = 0; mi < 4; mi++)
#pragma unroll
        for (int ni = 0; ni < 4; ni++)
          acc[mi][ni] = __builtin_amdgcn_mfma_f32_16x16x32_bf16(
              af[mi], bfr[ni], acc[mi][ni], 0, 0, 0);
    }
    __syncthreads();  // all waves done reading before next gload_lds overwrite
  }

  // epilogue: bias + RoPE (inline cos/sin)
  const int seg = (wt < 16) ? 1 : 0;  // 1=K, 0=Q
  const int head = wt & 15;
  u16* dst = seg ? Kw : Qw;
  float bv[4];
#pragma unroll
  for (int ni = 0; ni < 4; ni++)
    bv[ni] = bias[(head * 3 + seg) * 128 + ntoff[ni] + l16];
  const float RC = 0.20762050593045951f;  // log2(10000)/64
  const float f0 = exp2f(-(float)(wn + l16) * RC);
  const float f1 = exp2f(-(float)(wn + 16 + l16) * RC);

#pragma unroll
  for (int mi = 0; mi < 4; mi++) {
#pragma unroll
    for (int reg = 0; reg < 4; reg++) {
      int r = rowA0 + wm + mi * 16 + quad * 4 + reg;
      int s = r >> 1, b = r & 1;
      size_t base = ((size_t)(b * NH + head) * SEQ + s) * HD;
      float sv, cv;
      sincosf((float)s * f0, &sv, &cv);
      {
        float lo = acc[mi][0][reg] + bv[0];
        float hi = acc[mi][2][reg] + bv[2];
        dst[base + wn + l16] = f2bf(lo * cv - hi * sv);
        dst[base + wn + l16 + 64] = f2bf(hi * cv + lo * sv);
      }
      sincosf((float)s * f1, &sv, &cv);
      {
        float lo = acc[mi][1][reg] + bv[1];
        float hi = acc[mi][3][reg] + bv[3];
        dst[base + wn + 16 + l16] = f2bf(lo * cv - hi * sv);
        dst[base + wn + 16 + l16 + 64] = f2bf(hi * cv + lo * sv);
      }
    }
  }
}

// ---------------- V projection: pure gload_lds (wvw in d_out scratch) -------
__global__ __launch_bounds__(256, 2) void qkv_v(
    const u16* __restrict__ Ah, const u16* __restrict__ wvw,
    const float* __restrict__ bias, u16* __restrict__ Vt) {
  __shared__ __align__(16) u16 As[128 * 64];
  __shared__ __align__(16) u16 Bs[128 * 64];
  const int tid = threadIdx.x;
  const int wv = tid >> 6, lane = tid & 63;
  const int quad = lane >> 4, l16 = lane & 15;
  const int head = blockIdx.x;  // 0..15
  const int bm = blockIdx.y;
  const int rowA0 = bm * 128;
  const int wm = (wv >> 1) * 64;
  const int wn = (wv & 1) * 32;
  const int ntoff[4] = {wn, wn + 16, wn + 64, wn + 80};

  const int lrow = wv * 32 + (lane >> 3);
  const int lcol = (lane & 7) * 8;
  const u16* Ag = Ah + (size_t)(rowA0 + lrow) * HID + lcol;
  const u16* Bg = wvw + ((size_t)head * 128 + lrow) * HID + lcol;
  u16* Al = &As[(wv * 32) * 64];
  u16* Bl = &Bs[(wv * 32) * 64];

  floatx4 acc[4][4];
#pragma unroll
  for (int i = 0; i < 4; i++)
#pragma unroll
    for (int j = 0; j < 4; j++) acc[i][j] = (floatx4){0.f, 0.f, 0.f, 0.f};

  for (int kb = 0; kb < HID; kb += 64) {
#pragma unroll
    for (int j = 0; j < 4; j++) {
      gl16(Ag + (size_t)j * 8 * HID + kb, Al + j * 8 * 64);
      gl16(Bg + (size_t)j * 8 * HID + kb, Bl + j * 8 * 64);
    }
    __syncthreads();
#pragma unroll
    for (int ks = 0; ks < 64; ks += 32) {
      bf16x8 af[4], bfr[4];
#pragma unroll
      for (int mi = 0; mi < 4; mi++)
        af[mi] = *(const bf16x8*)&As[(wm + mi * 16 + l16) * 64 + ks + quad * 8];
#pragma unroll
      for (int ni = 0; ni < 4; ni++)
        bfr[ni] = *(const bf16x8*)&Bs[(ntoff[ni] + l16) * 64 + ks + quad * 8];
#pragma unroll
      for (int mi = 0; mi < 4; mi++)
#pragma unroll
        for (int ni = 0; ni < 4; ni++)
          acc[mi][ni] = __builtin_amdgcn_mfma_f32_16x16x32_bf16(
              af[mi], bfr[ni], acc[mi][ni], 0, 0, 0);
    }
    __syncthreads();
  }

  float bv[4];
#pragma unroll
  for (int ni = 0; ni < 4; ni++)
    bv[ni] = bias[(head * 3 + 2) * 128 + ntoff[ni] + l16];
#pragma unroll
  for (int mi = 0; mi < 4; mi++) {
#pragma unroll
    for (int ni = 0; ni < 4; ni++) {
      int d = ntoff[ni] + l16;
#pragma unroll
      for (int reg = 0; reg < 4; reg++) {
        int r = rowA0 + wm + mi * 16 + quad * 4 + reg;
        int s = r >> 1, b = r & 1;
        Vt[((size_t)(b * NH + head) * HD + d) * SEQ + s] =
            f2bf(acc[mi][ni][reg] + bv[ni]);
      }
    }
  }
}

// ---- flash attention: R11 inner loop + XCD-locality swizzle ----------------
__global__ __launch_bounds__(256, 2) void attn(
    const u16* __restrict__ Qw, const u16* __restrict__ Kw,
    const u16* __restrict__ Vt, u16* __restrict__ ctx) {
  __shared__ __align__(16) u16 Ks[64 * 128];     // 16384 B, linear+XOR-swz
  __shared__ __align__(16) u16 Vs[128 * 64];     // 16384 B, linear+XOR-swz
  __shared__ __align__(16) u16 Pl[4 * 32 * 72];  // 18432 B, per-wave 32x64

  const int tid = threadIdx.x;
  const int wv = tid >> 6, lane = tid & 63;
  const int quad = lane >> 4, l16 = lane & 15;

  // XCD-locality decode (R15-verified: FETCH 110->25MB): wgid%8 = XCD.
  // wgid = (bh&7) + 8*((bh>>3)*16+x) -> all 16 blocks of a bh on XCD bh%8.
  // Balanced pairing: qt = ((bh_hi>>1)&1) ? 15-x : x (34 tiles per CU pair).
  const int lin = blockIdx.y * gridDim.x + blockIdx.x;
  const int xcdsel = lin & 7;
  const int k = lin >> 3;        // 0..63
  const int bh_hi = k >> 4;      // 0..3
  const int x = k & 15;
  const int bh = (bh_hi << 3) | xcdsel;
  const int qt = ((bh_hi >> 1) & 1) ? (15 - x) : x;

  const int b = bh >> 4, h = bh & 15;
  const int sw = qt * 128 + wv * 32;  // this wave's 32 q-rows
  const size_t bhoff = (size_t)bh * SEQ * HD;

  bf16x8 qf[2][4];
#pragma unroll
  for (int mi = 0; mi < 2; mi++)
#pragma unroll
    for (int kc = 0; kc < 4; kc++)
      qf[mi][kc] = *(const bf16x8*)&Qw[bhoff +
                                       (size_t)(sw + mi * 16 + l16) * HD +
                                       kc * 32 + quad * 8];

  floatx4 o[2][8];
#pragma unroll
  for (int mi = 0; mi < 2; mi++)
#pragma unroll
    for (int ni = 0; ni < 8; ni++) o[mi][ni] = (floatx4){0.f, 0.f, 0.f, 0.f};
  float mst[2][4], lst[2][4];
#pragma unroll
  for (int mi = 0; mi < 2; mi++)
#pragma unroll
    for (int r = 0; r < 4; r++) { mst[mi][r] = -1e30f; lst[mi][r] = 0.f; }

  const int nt = qt * 2 + 2;
  // log2-domain softmax (R10/R11-proven): scale*log2e folded; mask=-10000*log2e
  const float SCL2 = 0.088388347648318447f * 1.442695040888963f;
  const float MSK2 = -10000.0f * 1.442695040888963f;

// stage K/V tile tt (single buffer); src pre-swizzled 16B unit u -> u^(row&7)
#define STAGE(tt)                                                              \
  {                                                                            \
    _Pragma("unroll") for (int i = 0; i < 4; i++) {                            \
      int c = i * 256 + tid;                                                   \
      int rk = c >> 4, uk = c & 15;                                            \
      gl16(&Kw[bhoff + (size_t)((tt) * 64 + rk) * HD + (uk ^ (rk & 7)) * 8],   \
           &Ks[(i * 256 + wv * 64) * 8]);                                      \
      int rv_ = c >> 3, uv = c & 7;                                            \
      gl16(&Vt[bhoff + (size_t)rv_ * SEQ + (tt) * 64 + (uv ^ (rv_ & 7)) * 8],  \
           &Vs[(i * 256 + wv * 64) * 8]);                                      \
    }                                                                          \
  }

  for (int t = 0; t < nt; t++) {
    __syncthreads();  // all waves done reading Ks/Vs of prev tile
    STAGE(t);
    __syncthreads();  // drains vmcnt(0): tiles ready

    const bool active = (t * 64 <= sw + 31);
    if (active) {
      floatx4 sa[2][4];
#pragma unroll
      for (int mi = 0; mi < 2; mi++)
#pragma unroll
        for (int ni = 0; ni < 4; ni++) sa[mi][ni] = (floatx4){0.f, 0.f, 0.f, 0.f};
      __builtin_amdgcn_s_setprio(1);
#pragma unroll
      for (int kc = 0; kc < 4; kc++) {
        bf16x8 kf[4];
#pragma unroll
        for (int ni = 0; ni < 4; ni++)
          kf[ni] = *(const bf16x8*)&Ks[(ni * 16 + l16) * 128 +
                                       (((kc * 4 + quad) ^ (l16 & 7)) * 8)];
#pragma unroll
        for (int mi = 0; mi < 2; mi++)
#pragma unroll
          for (int ni = 0; ni < 4; ni++)
            sa[mi][ni] = __builtin_amdgcn_mfma_f32_16x16x32_bf16(
                qf[mi][kc], kf[ni], sa[mi][ni], 0, 0, 0);
      }
      __builtin_amdgcn_s_setprio(0);

      // online softmax per row (R11 exact: always mask, always rescale)
      float alpha[2][4];
#pragma unroll
      for (int mi = 0; mi < 2; mi++) {
#pragma unroll
        for (int reg = 0; reg < 4; reg++) {
          int sq = sw + mi * 16 + quad * 4 + reg;
          float rv[4];
#pragma unroll
          for (int ni = 0; ni < 4; ni++) {
            int sk = t * 64 + ni * 16 + l16;
            float v = sa[mi][ni][reg] * SCL2;
            if (sk > sq) v = MSK2;
            rv[ni] = v;
          }
          float rmax = fmaxf(fmaxf(rv[0], rv[1]), fmaxf(rv[2], rv[3]));
          rmax = fmaxf(rmax, __shfl_xor(rmax, 1));
          rmax = fmaxf(rmax, __shfl_xor(rmax, 2));
          rmax = fmaxf(rmax, __shfl_xor(rmax, 4));
          rmax = fmaxf(rmax, __shfl_xor(rmax, 8));
          float mn = fmaxf(mst[mi][reg], rmax);
          float al = exp2f(mst[mi][reg] - mn);
          float rs = 0.f;
#pragma unroll
          for (int ni = 0; ni < 4; ni++) {
            float p = exp2f(rv[ni] - mn);
            rs += p;
            Pl[wv * 2304 + (mi * 16 + quad * 4 + reg) * 72 + ni * 16 + l16] =
                f2bf(p);
          }
          rs += __shfl_xor(rs, 1);
          rs += __shfl_xor(rs, 2);
          rs += __shfl_xor(rs, 4);
          rs += __shfl_xor(rs, 8);
          lst[mi][reg] = lst[mi][reg] * al + rs;
          mst[mi][reg] = mn;
          alpha[mi][reg] = al;
        }
      }
#pragma unroll
      for (int mi = 0; mi < 2; mi++)
#pragma unroll
        for (int ni = 0; ni < 8; ni++)
#pragma unroll
          for (int reg = 0; reg < 4; reg++)
            o[mi][ni][reg] *= alpha[mi][reg];

      // PV: P is wave-private (same-wave ds ordering) -> no barrier
      __builtin_amdgcn_s_setprio(1);
#pragma unroll
      for (int kc = 0; kc < 2; kc++) {
        bf16x8 pf[2];
#pragma unroll
        for (int mi = 0; mi < 2; mi++)
          pf[mi] = *(const bf16x8*)&Pl[wv * 2304 + (mi * 16 + l16) * 72 +
                                       kc * 32 + quad * 8];
#pragma unroll
        for (int ni = 0; ni < 8; ni++) {
          bf16x8 vf = *(const bf16x8*)&Vs[(ni * 16 + l16) * 64 +
                                          (((kc * 4 + quad) ^ (l16 & 7)) * 8)];
#pragma unroll
          for (int mi = 0; mi < 2; mi++)
            o[mi][ni] = __builtin_amdgcn_mfma_f32_16x16x32_bf16(
                pf[mi], vf, o[mi][ni], 0, 0, 0);
        }
      }
      __builtin_amdgcn_s_setprio(0);
    }
  }

  // final 1/l and store ctx [s][b][h*128+d]
#pragma unroll
  for (int mi = 0; mi < 2; mi++) {
#pragma unroll
    for (int reg = 0; reg < 4; reg++) {
      float inv = 1.0f / lst[mi][reg];
      int sq = sw + mi * 16 + quad * 4 + reg;
      size_t rbase = ((size_t)(sq * BATCH + b)) * HID + h * HD;
#pragma unroll
      for (int ni = 0; ni < 8; ni++)
        ctx[rbase + ni * 16 + l16] = f2bf(o[mi][ni][reg] * inv);
    }
  }
#undef STAGE
}

// ---------- dense GEMM (ctx bf16 @ wd bf16, gload_lds both) -> FP32 out -----
__global__ __launch_bounds__(256, 2) void dense_gemm(
    const u16* __restrict__ A, const u16* __restrict__ Wd,
    float* __restrict__ out) {
  __shared__ __align__(16) u16 As[128 * 64];
  __shared__ __align__(16) u16 Bs[128 * 64];
  const int tid = threadIdx.x;
  const int wv = tid >> 6, lane = tid & 63;
  const int quad = lane >> 4, l16 = lane & 15;
  const int bn = blockIdx.x, bm = blockIdx.y;
  const int rowA0 = bm * 128, rowB0 = bn * 128;
  const int wm = (wv >> 1) * 64;
  const int wn = (wv & 1) * 64;
  const int ntoff[4] = {wn, wn + 16, wn + 32, wn + 48};

  const int lrow = wv * 32 + (lane >> 3);
  const int lcol = (lane & 7) * 8;
  const u16* Ag = A + (size_t)(rowA0 + lrow) * HID + lcol;
  const u16* Bg = Wd + (size_t)(rowB0 + lrow) * HID + lcol;
  u16* Al = &As[(wv * 32) * 64];
  u16* Bl = &Bs[(wv * 32) * 64];

  floatx4 acc[4][4];
#pragma unroll
  for (int i = 0; i < 4; i++)
#pragma unroll
    for (int j = 0; j < 4; j++) acc[i][j] = (floatx4){0.f, 0.f, 0.f, 0.f};

  for (int kb = 0; kb < HID; kb += 64) {
#pragma unroll
    for (int j = 0; j < 4; j++) {
      gl16(Ag + (size_t)j * 8 * HID + kb, Al + j * 8 * 64);
      gl16(Bg + (size_t)j * 8 * HID + kb, Bl + j * 8 * 64);
    }
    __syncthreads();
#pragma unroll
    for (int ks = 0; ks < 64; ks += 32) {
      bf16x8 af[4], bfr[4];
#pragma unroll
      for (int mi = 0; mi < 4; mi++)
        af[mi] = *(const bf16x8*)&As[(wm + mi * 16 + l16) * 64 + ks + quad * 8];
#pragma unroll
      for (int ni = 0; ni < 4; ni++)
        bfr[ni] = *(const bf16x8*)&Bs[(ntoff[ni] + l16) * 64 + ks + quad * 8];
#pragma unroll
      for (int mi = 0; mi < 4; mi++)
#pragma unroll
        for (int ni = 0; ni < 4; ni++)
          acc[mi][ni] = __builtin_amdgcn_mfma_f32_16x16x32_bf16(
              af[mi], bfr[ni], acc[mi][ni], 0, 0, 0);
    }
    __syncthreads();
  }

#pragma unroll
  for (int mi = 0; mi < 4; mi++)
#pragma unroll
    for (int reg = 0; reg < 4; reg++) {
      int r = rowA0 + wm + mi * 16 + quad * 4 + reg;
#pragma unroll
      for (int ni = 0; ni < 4; ni++)
        out[(size_t)r * HID + bn * 128 + ntoff[ni] + l16] = acc[mi][ni][reg];
    }
}

// ---------------- bias passthrough (fp32 in -> fp32 out tail) ----------------
__global__ void copy_bias(const float* __restrict__ bd, float* __restrict__ out) {
  int i = blockIdx.x * 256 + threadIdx.x;
  if (i < HID) out[(size_t)SEQ * BATCH * HID + i] = bd[i];
}

extern "C" void kernel_launch(void* const* d_in, const int* in_sizes, int n_in,
                              void* d_out, int out_size, void* d_ws,
                              size_t ws_size, hipStream_t stream) {
  // Resolve inputs BY ELEMENT COUNT (dtype-independent):
  //   hidden 8388608, mask 4194304 (unused, precedes w_dense), w_qkv 12582912,
  //   b_qkv 6144, w_dense 4194304 (LAST match wins), b_dense 2048.
  const float *hidden = nullptr, *w_qkv = nullptr, *b_qkv = nullptr;
  const float *w_dense = nullptr, *b_dense = nullptr;
  for (int i = 0; i < n_in; i++) {
    long s = in_sizes[i];
    if (s == 8388608L) hidden = (const float*)d_in[i];
    else if (s == 12582912L) w_qkv = (const float*)d_in[i];
    else if (s == 6144L) b_qkv = (const float*)d_in[i];
    else if (s == 4194304L) w_dense = (const float*)d_in[i];  // last wins
    else if (s == 2048L) b_dense = (const float*)d_in[i];
  }
  float* out = (float*)d_out;

  // Workspace: 64 MiB, time-multiplexed:
  //   [ 0,16M) Qw                       ... later wd (8M, after attn)
  //   [16,32M) Kw
  //   [32,48M) wb K/Q tiles (dead after qkv_qk) -> Vt (written by qkv_v)
  //   [48,64M) Ah bf16 hidden -> ctx (written by attn)
  // wvw (bf16 V-weight tiles, 8M) lives in d_out scratch (dead until
  // dense_gemm overwrites it).
  char* ws = (char*)d_ws;
  u16* Qw = (u16*)(ws);                 // [ 0,16M)
  u16* Kw = (u16*)(ws + 16777216ll);    // [16,32M)
  u16* Vt = (u16*)(ws + 33554432ll);    // [32,48M) after qkv_v
  u16* wb = (u16*)(ws + 33554432ll);    // [32,48M) K/Q bf16 tiles
  u16* Ah = (u16*)(ws + 50331648ll);    // [48,64M) bf16 hidden (dead by attn)
  u16* ctx = (u16*)(ws + 50331648ll);   // [48,64M) after attn
  u16* wd = (u16*)(ws);                 // [0,8M) bf16 w_dense (after attn)
  u16* wvw = (u16*)d_out;               // d_out scratch (dead after qkv_v)

  cvt_inputs<<<dim3(10240), dim3(256), 0, stream>>>(w_qkv, hidden, wb, Ah, wvw);
  qkv_qk<<<dim3(32, 32), dim3(256), 0, stream>>>(Ah, wb, b_qkv, Qw, Kw);
  qkv_v<<<dim3(16, 32), dim3(256), 0, stream>>>(Ah, wvw, b_qkv, Vt);
  attn<<<dim3(16, 32), dim3(256), 0, stream>>>(Qw, Kw, Vt, ctx);
  cvt_wd<<<dim3(2048), dim3(256), 0, stream>>>(w_dense, wd);
  dense_gemm<<<dim3(16, 32), dim3(256), 0, stream>>>(ctx, wd, out);
  copy_bias<<<dim3(8), dim3(256), 0, stream>>>(b_dense, out);
}

// Round 9
// 422.140 us; speedup vs baseline: 1.1535x; 1.0723x over previous
//
#include <hip/hip_runtime.h>
#include <cstdint>
#include <math.h>

// ---------------------------------------------------------------------------
// ParallelAttention (GPT-NeoX style), MI355X gfx950.
//   SEQ=2048 BATCH=2 HID=2048 NH=16 HD=128, causal mask, RoPE full head dim.
// INTERFACE (established R0-R7): fp32 inputs, fp32 output, inputs resolved by
//   element count (w_dense = LAST 4194304 match; mask unused).
// R9: GEMMs on m97 structure (bf16 pre-convert + global_load_lds w16).
// R10 FAILED: 512-thr attn spilled -- root cause (R17 rediagnosis): prefetch
//   regs + LDS 52224 allowed 3 blocks/CU so compiler targeted 6 waves/SIMD
//   (64-VGPR class). NOT the 8-wave geometry itself.
// R11: attn 4-wave + gload_lds K/V (pre-swizzled src + XOR read). 133us.
// R12 FAILED: wvw aliased Vt. R13 dbuf 154. R14 split-K 160. R15: XCD swizzle
//   verified (FETCH 110->25MB) but riders cost ~20us across 3 structures.
// R16: R11 inner loop + XCD swizzle only: attn 132.5us, total 452.7.
//   Counters: HBM 4%, Mfma 10.7, VALU 32, Occ 12.6 -> purely occupancy/
//   latency-bound at 2 waves/SIMD (VGPR 116 supports 4).
// R17: (1) attn -> 8 waves x 16 q-rows (512 thr), no prefetch regs, LDS
//   padded to 55.8K so ONLY 2 blocks/CU fit -> compiler targets 4 waves/SIMD
//   (128-VGPR class) -> 16 waves/CU, 2x latency hiding. (2) qkv_qk+qkv_v
//   merged (Vt moved to d_out[8M,24M) to avoid R12's wb alias). (3) bias
//   copy merged into cvt_inputs. 7 -> 5 launches.
// MFMA 16x16x32 bf16: A/B row=lane&15, k=(lane>>4)*8+j; C/D col=lane&15,
//   row=(lane>>4)*4+reg (verified m89/m91).
// global_load_lds: LDS dest is wave-uniform base + lane*16B (m104/m108) --
//   LDS must be LINEAR, source address is per-lane (pre-swizzle there).
// ---------------------------------------------------------------------------

typedef unsigned short u16;
typedef __bf16 bf16x8 __attribute__((ext_vector_type(8)));
typedef float floatx4 __attribute__((ext_vector_type(4)));

#define SEQ 2048
#define BATCH 2
#define HID 2048
#define NH 16
#define HD 128

__device__ __forceinline__ u16 f2bf(float f) {
  union { float f; uint32_t u; } v; v.f = f;
  uint32_t u = v.u;
  return (u16)((u + 0x7FFFu + ((u >> 16) & 1u)) >> 16);
}

// pack 8 fp32 -> 8 bf16 (RNE) and store 16B
__device__ __forceinline__ void st8_bf16(u16* dst, const float* s) {
  uint32_t pk[4];
#pragma unroll
  for (int j = 0; j < 4; j++)
    pk[j] = (uint32_t)f2bf(s[2 * j]) | ((uint32_t)f2bf(s[2 * j + 1]) << 16);
  *(uint4*)dst = make_uint4(pk[0], pk[1], pk[2], pk[3]);
}

// async global->LDS, 16B per lane; lds base must be wave-uniform
__device__ __forceinline__ void gl16(const u16* g, u16* l) {
  __builtin_amdgcn_global_load_lds(
      (const __attribute__((address_space(1))) void*)g,
      (__attribute__((address_space(3))) void*)l, 16, 0, 0);
}

// ------- input conversion: w_qkv K/Q tiles, hidden, V tiles; + bias tail ----
// wb tile order: [K head 0..15][Q head 0..15]; src K h = 3h+1, Q h = 3h.
// V tiles (blk 8192..10239) -> wvw (d_out scratch). blk 10240 = bias tail.
__global__ __launch_bounds__(256) void cvt_inputs(
    const float* __restrict__ W, const float* __restrict__ Hid,
    u16* __restrict__ wb, u16* __restrict__ Ah, u16* __restrict__ wvw,
    const float* __restrict__ bd, float* __restrict__ out) {
  const int blk = blockIdx.x;
  const int c0 = threadIdx.x * 8;
  if (blk == 10240) {  // bias passthrough: fp32 -> out tail (never clobbered)
#pragma unroll
    for (int j = 0; j < 8; j++)
      out[(size_t)SEQ * BATCH * HID + c0 + j] = bd[c0 + j];
    return;
  }
  const float* src;
  u16* dst;
  if (blk < 4096) {
    int dt = blk >> 7, r = blk & 127;
    int srow = (dt < 16) ? ((dt * 3 + 1) * 128 + r) : (((dt - 16) * 3) * 128 + r);
    src = W + (size_t)srow * HID;
    dst = wb + (size_t)blk * HID;
  } else if (blk < 8192) {
    int r = blk - 4096;
    src = Hid + (size_t)r * HID;
    dst = Ah + (size_t)r * HID;
  } else {
    int v = blk - 8192;  // 0..2047
    int h = v >> 7, r = v & 127;
    src = W + (size_t)((h * 3 + 2) * 128 + r) * HID;
    dst = wvw + (size_t)v * HID;
  }
  float t[8];
  *(floatx4*)&t[0] = *(const floatx4*)(src + c0);
  *(floatx4*)&t[4] = *(const floatx4*)(src + c0 + 4);
  st8_bf16(dst + c0, t);
}

// ---------------- w_dense fp32 -> bf16 --------------------------------------
__global__ __launch_bounds__(256) void cvt_wd(const float* __restrict__ W,
                                              u16* __restrict__ wd) {
  const int r = blockIdx.x;
  const int c0 = threadIdx.x * 8;
  float t[8];
  const float* src = W + (size_t)r * HID;
  *(floatx4*)&t[0] = *(const floatx4*)(src + c0);
  *(floatx4*)&t[4] = *(const floatx4*)(src + c0 + 4);
  st8_bf16(wd + (size_t)r * HID + c0, t);
}

// ------- QKV projection (merged): bf16 @ bf16, gload_lds both operands ------
// blockIdx.x 0..15 = K head, 16..31 = Q head, 32..47 = V head.
__global__ __launch_bounds__(256, 2) void qkv(
    const u16* __restrict__ Ah, const u16* __restrict__ wb,
    const u16* __restrict__ wvw, const float* __restrict__ bias,
    u16* __restrict__ Qw, u16* __restrict__ Kw, u16* __restrict__ Vt) {
  __shared__ __align__(16) u16 As[128 * 64];
  __shared__ __align__(16) u16 Bs[128 * 64];
  const int tid = threadIdx.x;
  const int wv = tid >> 6, lane = tid & 63;
  const int quad = lane >> 4, l16 = lane & 15;
  const int wt = blockIdx.x;  // 0..47
  const bool isv = (wt >= 32);
  const int bm = blockIdx.y;
  const int rowA0 = bm * 128;
  const int wm = (wv >> 1) * 64;
  const int wn = (wv & 1) * 32;
  const int ntoff[4] = {wn, wn + 16, wn + 64, wn + 80};

  const int lrow = wv * 32 + (lane >> 3);
  const int lcol = (lane & 7) * 8;
  const u16* Ag = Ah + (size_t)(rowA0 + lrow) * HID + lcol;
  const u16* Bg = (isv ? wvw + ((size_t)(wt - 32) * 128 + lrow) * HID
                       : wb + ((size_t)wt * 128 + lrow) * HID) + lcol;
  u16* Al = &As[(wv * 32) * 64];  // wave-uniform
  u16* Bl = &Bs[(wv * 32) * 64];

  floatx4 acc[4][4];
#pragma unroll
  for (int i = 0; i < 4; i++)
#pragma unroll
    for (int j = 0; j < 4; j++) acc[i][j] = (floatx4){0.f, 0.f, 0.f, 0.f};

  for (int kb = 0; kb < HID; kb += 64) {
#pragma unroll
    for (int j = 0; j < 4; j++) {
      gl16(Ag + (size_t)j * 8 * HID + kb, Al + j * 8 * 64);
      gl16(Bg + (size_t)j * 8 * HID + kb, Bl + j * 8 * 64);
    }
    __syncthreads();  // drains vmcnt(0): LDS tiles ready
#pragma unroll
    for (int ks = 0; ks < 64; ks += 32) {
      bf16x8 af[4], bfr[4];
#pragma unroll
      for (int mi = 0; mi < 4; mi++)
        af[mi] = *(const bf16x8*)&As[(wm + mi * 16 + l16) * 64 + ks + quad * 8];
#pragma unroll
      for (int ni = 0; ni < 4; ni++)
        bfr[ni] = *(const bf16x8*)&Bs[(ntoff[ni] + l16) * 64 + ks + quad * 8];
#pragma unroll
      for (int mi = 0; mi < 4; mi++)
#pragma unroll
        for (int ni = 0; ni < 4; ni++)
          acc[mi][ni] = __builtin_amdgcn_mfma_f32_16x16x32_bf16(
              af[mi], bfr[ni], acc[mi][ni], 0, 0, 0);
    }
    __syncthreads();  // all waves done reading before next gload_lds overwrite
  }

  if (!isv) {
    // epilogue: bias + RoPE (inline cos/sin)
    const int seg = (wt < 16) ? 1 : 0;  // 1=K, 0=Q
    const int head = wt & 15;
    u16* dst = seg ? Kw : Qw;
    float bv[4];
#pragma unroll
    for (int ni = 0; ni < 4; ni++)
      bv[ni] = bias[(head * 3 + seg) * 128 + ntoff[ni] + l16];
    const float RC = 0.20762050593045951f;  // log2(10000)/64
    const float f0 = exp2f(-(float)(wn + l16) * RC);
    const float f1 = exp2f(-(float)(wn + 16 + l16) * RC);

#pragma unroll
    for (int mi = 0; mi < 4; mi++) {
#pragma unroll
      for (int reg = 0; reg < 4; reg++) {
        int r = rowA0 + wm + mi * 16 + quad * 4 + reg;
        int s = r >> 1, b = r & 1;
        size_t base = ((size_t)(b * NH + head) * SEQ + s) * HD;
        float sv, cv;
        sincosf((float)s * f0, &sv, &cv);
        {
          float lo = acc[mi][0][reg] + bv[0];
          float hi = acc[mi][2][reg] + bv[2];
          dst[base + wn + l16] = f2bf(lo * cv - hi * sv);
          dst[base + wn + l16 + 64] = f2bf(hi * cv + lo * sv);
        }
        sincosf((float)s * f1, &sv, &cv);
        {
          float lo = acc[mi][1][reg] + bv[1];
          float hi = acc[mi][3][reg] + bv[3];
          dst[base + wn + 16 + l16] = f2bf(lo * cv - hi * sv);
          dst[base + wn + 16 + l16 + 64] = f2bf(hi * cv + lo * sv);
        }
      }
    }
  } else {
    const int head = wt - 32;
    float bv[4];
#pragma unroll
    for (int ni = 0; ni < 4; ni++)
      bv[ni] = bias[(head * 3 + 2) * 128 + ntoff[ni] + l16];
#pragma unroll
    for (int mi = 0; mi < 4; mi++) {
#pragma unroll
      for (int ni = 0; ni < 4; ni++) {
        int d = ntoff[ni] + l16;
#pragma unroll
        for (int reg = 0; reg < 4; reg++) {
          int r = rowA0 + wm + mi * 16 + quad * 4 + reg;
          int s = r >> 1, b = r & 1;
          Vt[((size_t)(b * NH + head) * HD + d) * SEQ + s] =
              f2bf(acc[mi][ni][reg] + bv[ni]);
        }
      }
    }
  }
}

// ---- flash attention: 8 waves x 16 q-rows, gload_lds K/V, XCD swizzle ------
__global__ __launch_bounds__(512, 4) void attn(
    const u16* __restrict__ Qw, const u16* __restrict__ Kw,
    const u16* __restrict__ Vt, u16* __restrict__ ctx) {
  __shared__ __align__(16) u16 Ks[64 * 128];          // 16384 B
  __shared__ __align__(16) u16 Vs[128 * 64 + 2304];   // 20992 B (pad: see note)
  __shared__ __align__(16) u16 Pl[8 * 16 * 72];       // 18432 B
  // total 55808 B > 160K/3 -> max 2 blocks/CU -> compiler targets 4 waves/SIMD
  // (128-VGPR class), preventing R10's 64-VGPR spill mode.

  const int tid = threadIdx.x;  // 0..511
  const int wv = tid >> 6, lane = tid & 63;
  const int quad = lane >> 4, l16 = lane & 15;

  // XCD-locality decode (R15-verified: FETCH 110->25MB): wgid%8 = XCD.
  const int lin = blockIdx.y * gridDim.x + blockIdx.x;
  const int xcdsel = lin & 7;
  const int k = lin >> 3;        // 0..63
  const int bh_hi = k >> 4;      // 0..3
  const int x = k & 15;
  const int bh = (bh_hi << 3) | xcdsel;
  const int qt = ((bh_hi >> 1) & 1) ? (15 - x) : x;

  const int b = bh >> 4, h = bh & 15;
  const int sw = qt * 128 + wv * 16;  // this wave's 16 q-rows
  const size_t bhoff = (size_t)bh * SEQ * HD;

  bf16x8 qf[4];
#pragma unroll
  for (int kc = 0; kc < 4; kc++)
    qf[kc] = *(const bf16x8*)&Qw[bhoff + (size_t)(sw + l16) * HD + kc * 32 +
                                 quad * 8];

  floatx4 o[8];
#pragma unroll
  for (int ni = 0; ni < 8; ni++) o[ni] = (floatx4){0.f, 0.f, 0.f, 0.f};
  float mst[4], lst[4];
#pragma unroll
  for (int r = 0; r < 4; r++) { mst[r] = -1e30f; lst[r] = 0.f; }

  const int nt = qt * 2 + 2;
  const float SCL2 = 0.088388347648318447f * 1.442695040888963f;
  const float MSK2 = -10000.0f * 1.442695040888963f;

// stage K/V tile tt; src pre-swizzled 16B unit u -> u^(row&7); 512 threads
// cover 1024 units each of K and V in 2 rounds.
#define STAGE(tt)                                                              \
  {                                                                            \
    _Pragma("unroll") for (int i = 0; i < 2; i++) {                            \
      int c = i * 512 + tid;                                                   \
      int rk = c >> 4, uk = c & 15;                                            \
      gl16(&Kw[bhoff + (size_t)((tt) * 64 + rk) * HD + (uk ^ (rk & 7)) * 8],   \
           &Ks[(i * 512 + wv * 64) * 8]);                                      \
      int rv_ = c >> 3, uv = c & 7;                                            \
      gl16(&Vt[bhoff + (size_t)rv_ * SEQ + (tt) * 64 + (uv ^ (rv_ & 7)) * 8],  \
           &Vs[(i * 512 + wv * 64) * 8]);                                      \
    }                                                                          \
  }

  for (int t = 0; t < nt; t++) {
    __syncthreads();  // all waves done reading Ks/Vs of prev tile
    STAGE(t);
    __syncthreads();  // drains vmcnt(0): tiles ready

    const bool active = (t * 64 <= sw + 15);
    if (active) {
      floatx4 sa[4];
#pragma unroll
      for (int ni = 0; ni < 4; ni++) sa[ni] = (floatx4){0.f, 0.f, 0.f, 0.f};
      __builtin_amdgcn_s_setprio(1);
#pragma unroll
      for (int kc = 0; kc < 4; kc++) {
        bf16x8 kf[4];
#pragma unroll
        for (int ni = 0; ni < 4; ni++)
          kf[ni] = *(const bf16x8*)&Ks[(ni * 16 + l16) * 128 +
                                       (((kc * 4 + quad) ^ (l16 & 7)) * 8)];
#pragma unroll
        for (int ni = 0; ni < 4; ni++)
          sa[ni] = __builtin_amdgcn_mfma_f32_16x16x32_bf16(qf[kc], kf[ni],
                                                           sa[ni], 0, 0, 0);
      }
      __builtin_amdgcn_s_setprio(0);

      // online softmax per row (always mask, always rescale -- R16-proven)
      float alpha[4];
#pragma unroll
      for (int reg = 0; reg < 4; reg++) {
        const int rr = quad * 4 + reg;
        const int sq = sw + rr;
        float rv[4];
#pragma unroll
        for (int ni = 0; ni < 4; ni++) {
          int sk = t * 64 + ni * 16 + l16;
          float v = sa[ni][reg] * SCL2;
          if (sk > sq) v = MSK2;
          rv[ni] = v;
        }
        float rmax = fmaxf(fmaxf(rv[0], rv[1]), fmaxf(rv[2], rv[3]));
        rmax = fmaxf(rmax, __shfl_xor(rmax, 1));
        rmax = fmaxf(rmax, __shfl_xor(rmax, 2));
        rmax = fmaxf(rmax, __shfl_xor(rmax, 4));
        rmax = fmaxf(rmax, __shfl_xor(rmax, 8));
        float mn = fmaxf(mst[reg], rmax);
        float al = exp2f(mst[reg] - mn);
        float rs = 0.f;
#pragma unroll
        for (int ni = 0; ni < 4; ni++) {
          float p = exp2f(rv[ni] - mn);
          rs += p;
          Pl[wv * 1152 + rr * 72 + ni * 16 + l16] = f2bf(p);
        }
        rs += __shfl_xor(rs, 1);
        rs += __shfl_xor(rs, 2);
        rs += __shfl_xor(rs, 4);
        rs += __shfl_xor(rs, 8);
        lst[reg] = lst[reg] * al + rs;
        mst[reg] = mn;
        alpha[reg] = al;
      }
#pragma unroll
      for (int ni = 0; ni < 8; ni++)
#pragma unroll
        for (int reg = 0; reg < 4; reg++) o[ni][reg] *= alpha[reg];

      // PV: P is wave-private (same-wave ds ordering) -> no barrier
      __builtin_amdgcn_s_setprio(1);
#pragma unroll
      for (int kc = 0; kc < 2; kc++) {
        bf16x8 pf =
            *(const bf16x8*)&Pl[wv * 1152 + l16 * 72 + kc * 32 + quad * 8];
#pragma unroll
        for (int ni = 0; ni < 8; ni++) {
          bf16x8 vf = *(const bf16x8*)&Vs[(ni * 16 + l16) * 64 +
                                          (((kc * 4 + quad) ^ (l16 & 7)) * 8)];
          o[ni] = __builtin_amdgcn_mfma_f32_16x16x32_bf16(pf, vf, o[ni], 0, 0,
                                                          0);
        }
      }
      __builtin_amdgcn_s_setprio(0);
    }
  }

  // final 1/l and store ctx [s][b][h*128+d]
#pragma unroll
  for (int reg = 0; reg < 4; reg++) {
    float inv = 1.0f / lst[reg];
    int sq = sw + quad * 4 + reg;
    size_t rbase = ((size_t)(sq * BATCH + b)) * HID + h * HD;
#pragma unroll
    for (int ni = 0; ni < 8; ni++)
      ctx[rbase + ni * 16 + l16] = f2bf(o[ni][reg] * inv);
  }
#undef STAGE
}

// ---------- dense GEMM (ctx bf16 @ wd bf16, gload_lds both) -> FP32 out -----
__global__ __launch_bounds__(256, 2) void dense_gemm(
    const u16* __restrict__ A, const u16* __restrict__ Wd,
    float* __restrict__ out) {
  __shared__ __align__(16) u16 As[128 * 64];
  __shared__ __align__(16) u16 Bs[128 * 64];
  const int tid = threadIdx.x;
  const int wv = tid >> 6, lane = tid & 63;
  const int quad = lane >> 4, l16 = lane & 15;
  const int bn = blockIdx.x, bm = blockIdx.y;
  const int rowA0 = bm * 128, rowB0 = bn * 128;
  const int wm = (wv >> 1) * 64;
  const int wn = (wv & 1) * 64;
  const int ntoff[4] = {wn, wn + 16, wn + 32, wn + 48};

  const int lrow = wv * 32 + (lane >> 3);
  const int lcol = (lane & 7) * 8;
  const u16* Ag = A + (size_t)(rowA0 + lrow) * HID + lcol;
  const u16* Bg = Wd + (size_t)(rowB0 + lrow) * HID + lcol;
  u16* Al = &As[(wv * 32) * 64];
  u16* Bl = &Bs[(wv * 32) * 64];

  floatx4 acc[4][4];
#pragma unroll
  for (int i = 0; i < 4; i++)
#pragma unroll
    for (int j = 0; j < 4; j++) acc[i][j] = (floatx4){0.f, 0.f, 0.f, 0.f};

  for (int kb = 0; kb < HID; kb += 64) {
#pragma unroll
    for (int j = 0; j < 4; j++) {
      gl16(Ag + (size_t)j * 8 * HID + kb, Al + j * 8 * 64);
      gl16(Bg + (size_t)j * 8 * HID + kb, Bl + j * 8 * 64);
    }
    __syncthreads();
#pragma unroll
    for (int ks = 0; ks < 64; ks += 32) {
      bf16x8 af[4], bfr[4];
#pragma unroll
      for (int mi = 0; mi < 4; mi++)
        af[mi] = *(const bf16x8*)&As[(wm + mi * 16 + l16) * 64 + ks + quad * 8];
#pragma unroll
      for (int ni = 0; ni < 4; ni++)
        bfr[ni] = *(const bf16x8*)&Bs[(ntoff[ni] + l16) * 64 + ks + quad * 8];
#pragma unroll
      for (int mi = 0; mi < 4; mi++)
#pragma unroll
        for (int ni = 0; ni < 4; ni++)
          acc[mi][ni] = __builtin_amdgcn_mfma_f32_16x16x32_bf16(
              af[mi], bfr[ni], acc[mi][ni], 0, 0, 0);
    }
    __syncthreads();
  }

#pragma unroll
  for (int mi = 0; mi < 4; mi++)
#pragma unroll
    for (int reg = 0; reg < 4; reg++) {
      int r = rowA0 + wm + mi * 16 + quad * 4 + reg;
#pragma unroll
      for (int ni = 0; ni < 4; ni++)
        out[(size_t)r * HID + bn * 128 + ntoff[ni] + l16] = acc[mi][ni][reg];
    }
}

extern "C" void kernel_launch(void* const* d_in, const int* in_sizes, int n_in,
                              void* d_out, int out_size, void* d_ws,
                              size_t ws_size, hipStream_t stream) {
  // Resolve inputs BY ELEMENT COUNT (dtype-independent):
  //   hidden 8388608, mask 4194304 (unused, precedes w_dense), w_qkv 12582912,
  //   b_qkv 6144, w_dense 4194304 (LAST match wins), b_dense 2048.
  const float *hidden = nullptr, *w_qkv = nullptr, *b_qkv = nullptr;
  const float *w_dense = nullptr, *b_dense = nullptr;
  for (int i = 0; i < n_in; i++) {
    long s = in_sizes[i];
    if (s == 8388608L) hidden = (const float*)d_in[i];
    else if (s == 12582912L) w_qkv = (const float*)d_in[i];
    else if (s == 6144L) b_qkv = (const float*)d_in[i];
    else if (s == 4194304L) w_dense = (const float*)d_in[i];  // last wins
    else if (s == 2048L) b_dense = (const float*)d_in[i];
  }
  float* out = (float*)d_out;

  // Workspace (64 MiB):
  //   [ 0,16M) Qw                       ... later wd (8M, after attn)
  //   [16,32M) Kw
  //   [32,48M) wb K/Q bf16 tiles (live through qkv)
  //   [48,64M) Ah bf16 hidden -> ctx (written by attn)
  // d_out scratch (33.5 MB, overwritten only by dense_gemm at the end):
  //   [ 0, 8M) wvw bf16 V-weight tiles (dead after qkv)
  //   [ 8,24M) Vt bf16 [b][h][d][s]    (dead after attn)
  //   tail [33554432B ..) = bias output, written by cvt_inputs, untouched.
  char* ws = (char*)d_ws;
  u16* Qw = (u16*)(ws);                 // [ 0,16M)
  u16* Kw = (u16*)(ws + 16777216ll);    // [16,32M)
  u16* wb = (u16*)(ws + 33554432ll);    // [32,48M)
  u16* Ah = (u16*)(ws + 50331648ll);    // [48,64M) bf16 hidden (dead by attn)
  u16* ctx = (u16*)(ws + 50331648ll);   // [48,64M) after attn
  u16* wd = (u16*)(ws);                 // [0,8M) bf16 w_dense (after attn)
  u16* wvw = (u16*)d_out;               // d_out [0,8M)
  u16* Vt = (u16*)d_out + 4194304;      // d_out [8,24M)

  cvt_inputs<<<dim3(10241), dim3(256), 0, stream>>>(w_qkv, hidden, wb, Ah, wvw,
                                                    b_dense, out);
  qkv<<<dim3(48, 32), dim3(256), 0, stream>>>(Ah, wb, wvw, b_qkv, Qw, Kw, Vt);
  attn<<<dim3(16, 32), dim3(512), 0, stream>>>(Qw, Kw, Vt, ctx);
  cvt_wd<<<dim3(2048), dim3(256), 0, stream>>>(w_dense, wd);
  dense_gemm<<<dim3(16, 32), dim3(256), 0, stream>>>(ctx, wd, out);
}